// Round 4
// 1734.535 us; speedup vs baseline: 1.0676x; 1.0676x over previous
//
#include <hip/hip_runtime.h>

typedef __bf16 bf16;
typedef short s16x8 __attribute__((ext_vector_type(8)));
typedef float f32x4 __attribute__((ext_vector_type(4)));
typedef unsigned long long u64;

#define MFMA16(a, b, c) __builtin_amdgcn_mfma_f32_16x16x32_bf16((a), (b), (c), 0, 0, 0)
#define NROW 187   // cand rows per batch: 63 init + 2/iter
#define UROW 251   // unified rows: 64 leaf + 187 cand

__device__ __forceinline__ float sigf(float x) { return 1.0f / (1.0f + expf(-x)); }
__device__ __forceinline__ s16x8 ld8(const bf16* p) { return *(const s16x8*)p; }

__device__ __forceinline__ unsigned packhl(float v) {
    bf16 h = (bf16)v;
    bf16 l = (bf16)(v - (float)h);
    return (unsigned)__builtin_bit_cast(unsigned short, h) |
           ((unsigned)__builtin_bit_cast(unsigned short, l) << 16);
}
__device__ __forceinline__ u64 lda64(const unsigned* p) {
    return __hip_atomic_load((const u64*)p, __ATOMIC_RELAXED, __HIP_MEMORY_SCOPE_AGENT);
}
__device__ __forceinline__ float ldaf(const float* p) {
    return __hip_atomic_load(p, __ATOMIC_RELAXED, __HIP_MEMORY_SCOPE_AGENT);
}
__device__ __forceinline__ void staf(float* p, float v) {
    __hip_atomic_store(p, v, __ATOMIC_RELAXED, __HIP_MEMORY_SCOPE_AGENT);
}
__device__ __forceinline__ void stau(unsigned* p, unsigned v) {
    __hip_atomic_store(p, v, __ATOMIC_RELAXED, __HIP_MEMORY_SCOPE_AGENT);
}

// ---------------- device-global workspace (fp32 in / fp32 out) -------------
__device__ bf16  g_xhi[64 * 64 * 512], g_xlo[64 * 64 * 512];
__device__ bf16  g_wwhi[1024 * 512], g_wwlo[1024 * 512];
__device__ bf16  g_wchi[2560 * 1024], g_wclo[2560 * 1024];
__device__ bf16  g_hhi[64 * 64 * 512];              // leaf h hi (k_cells_init A)
__device__ bf16  g_hlo[64 * 64 * 512];              // leaf h lo
__device__ unsigned g_uhl[(size_t)64 * UROW * 512]; // unified h packed (hi|lo<<16)
__device__ float g_uc[(size_t)64 * UROW * 512];     // unified c fp32
__device__ float g_candh[(size_t)64 * NROW * 512];  // cand h fp32 (self-read only)
__device__ float g_spinit[64 * 63 * 32];
__device__ float g_spart[2 * 128 * 32];             // [parity][rg*16+row][fg]
__device__ int   g_bar[63 * 128];                   // [it][rg*16]

// ---------------- prep: all three fp32 -> bf16 hi/lo splits ----------------
__global__ __launch_bounds__(256) void k_prep(const float* __restrict__ x,
                                              const float* __restrict__ ww,
                                              const float* __restrict__ wc) {
    const int NX = 64 * 64 * 512, NW = 1024 * 512, NC = 2560 * 1024;
    int stride = gridDim.x * 256, i0 = blockIdx.x * 256 + threadIdx.x;
    for (int i = i0; i < NX; i += stride) {
        float v = x[i];
        bf16 h = (bf16)v;
        g_xhi[i] = h;
        g_xlo[i] = (bf16)(v - (float)h);
    }
    for (int i = i0; i < NW; i += stride) {
        float v = ww[i];
        bf16 h = (bf16)v;
        g_wwhi[i] = h;
        g_wwlo[i] = (bf16)(v - (float)h);
    }
    for (int i = i0; i < NC; i += stride) {
        float v = wc[i];
        bf16 h = (bf16)v;
        g_wchi[i] = h;
        g_wclo[i] = (bf16)(v - (float)h);
    }
}

// ---------------------------------------------------------------------------
// K0: leaf projection (M=4096, N=1024, K=512), 3-pass hi/lo MFMA.
// ---------------------------------------------------------------------------
__global__ __launch_bounds__(64) void k_leaf(const float* __restrict__ b_word) {
    int cg = blockIdx.x, rg = blockIdx.y;
    int lane = threadIdx.x, l15 = lane & 15, quad = lane >> 4;
    const bf16* axh = g_xhi + (size_t)(rg * 16 + l15) * 512;
    const bf16* axl = g_xlo + (size_t)(rg * 16 + l15) * 512;
    const bf16* bwh = g_wwhi + (size_t)(cg * 64 + l15) * 512;
    const bf16* bwl = g_wwlo + (size_t)(cg * 64 + l15) * 512;
    f32x4 acc[4] = {};
    for (int kc = 0; kc < 16; ++kc) {
        int k = kc * 32 + quad * 8;
        s16x8 aH = ld8(axh + k), aL = ld8(axl + k);
#pragma unroll
        for (int t = 0; t < 4; ++t) {
            s16x8 bH = ld8(bwh + (size_t)t * 16 * 512 + k);
            s16x8 bL = ld8(bwl + (size_t)t * 16 * 512 + k);
            acc[t] = MFMA16(aH, bH, acc[t]);
            acc[t] = MFMA16(aH, bL, acc[t]);
            acc[t] = MFMA16(aL, bH, acc[t]);
        }
    }
#pragma unroll
    for (int t = 0; t < 4; ++t) {
        int col = cg * 64 + t * 16 + l15;
        float bw = b_word[col];
#pragma unroll
        for (int r = 0; r < 4; ++r) {
            int m = rg * 16 + quad * 4 + r;
            int bb = m >> 6, sl = m & 63;
            float v = acc[t][r] + bw;
            if (col < 512) {
                bf16 hi = (bf16)v;
                g_hhi[(size_t)m * 512 + col] = hi;
                g_hlo[(size_t)m * 512 + col] = (bf16)(v - (float)hi);
                g_uhl[((size_t)bb * UROW + sl) * 512 + col] = packhl(v);
            } else {
                g_uc[((size_t)bb * UROW + sl) * 512 + (col - 512)] = v;
            }
        }
    }
}

// ---------------------------------------------------------------------------
// K1: initial candidates, all pairs (b,j) -> unified rows 64..126.
// ---------------------------------------------------------------------------
__global__ __launch_bounds__(64) void k_cells_init(const int* __restrict__ length,
                                                   const float* __restrict__ b_comp,
                                                   const float* __restrict__ q) {
    int fg = blockIdx.x;            // 0..31
    int rg = blockIdx.y;            // 0..62
    int lane = threadIdx.x, l15 = lane & 15, quad = lane >> 4;

    const bf16 *ahi[4], *alo[4];
#pragma unroll
    for (int t = 0; t < 4; ++t) {
        int r = rg * 64 + t * 16 + l15;      // pair row 0..4031
        int b = r / 63, j = r - b * 63;
        ahi[t] = g_hhi + (size_t)(b * 64 + j) * 512;
        alo[t] = g_hlo + (size_t)(b * 64 + j) * 512;
    }
    const bf16* wh = g_wchi + (size_t)(fg * 16 + l15) * 1024;
    const bf16* wl = g_wclo + (size_t)(fg * 16 + l15) * 1024;
    f32x4 acc[4][5] = {};
    for (int kc = 0; kc < 32; ++kc) {
        int k = kc * 32 + quad * 8;
        int kk = k & 511;
        size_t sh = (k < 512) ? 0 : 512;     // row j vs j+1 (contiguous rows)
        s16x8 aH[4], aL[4];
#pragma unroll
        for (int t = 0; t < 4; ++t) {
            aH[t] = ld8(ahi[t] + sh + kk);
            aL[t] = ld8(alo[t] + sh + kk);
        }
#pragma unroll
        for (int g = 0; g < 5; ++g) {
            s16x8 bH = ld8(wh + (size_t)g * 512 * 1024 + k);
            s16x8 bL = ld8(wl + (size_t)g * 512 * 1024 + k);
#pragma unroll
            for (int t = 0; t < 4; ++t) {
                acc[t][g] = MFMA16(aH[t], bH, acc[t][g]);
                acc[t][g] = MFMA16(aH[t], bL, acc[t][g]);
                acc[t][g] = MFMA16(aL[t], bH, acc[t][g]);
            }
        }
    }
    int col = fg * 16 + l15;
    float bc[5];
#pragma unroll
    for (int g = 0; g < 5; ++g) bc[g] = b_comp[g * 512 + col];
    float qv = q[col];
#pragma unroll
    for (int t = 0; t < 4; ++t) {
#pragma unroll
        for (int rr = 0; rr < 4; ++rr) {
            int R = rg * 64 + t * 16 + quad * 4 + rr;
            int B_ = R / 63, J = R - B_ * 63;
            bool act = (J <= length[B_] - 2);
            float gi = acc[t][0][rr] + bc[0];
            float fl = acc[t][1][rr] + bc[1];
            float fr = acc[t][2][rr] + bc[2];
            float gu = acc[t][3][rr] + bc[3];
            float go = acc[t][4][rr] + bc[4];
            float cl = g_uc[((size_t)B_ * UROW + J) * 512 + col];
            float cr = g_uc[((size_t)B_ * UROW + J + 1) * 512 + col];
            float cn = cl * sigf(fl + 1.0f) + cr * sigf(fr + 1.0f) + tanhf(gu) * sigf(gi);
            float hn = sigf(go) * tanhf(cn);
            float sp = hn * qv;
#pragma unroll
            for (int off = 1; off < 16; off <<= 1) sp += __shfl_xor(sp, off, 16);
            if (act) {
                size_t o = ((size_t)B_ * UROW + 64 + J) * 512 + col;
                g_uhl[o] = packhl(hn);
                g_uc[o] = cn;
                g_candh[((size_t)B_ * NROW + J) * 512 + col] = hn;
                if (l15 == 0) g_spinit[(size_t)R * 32 + fg] = sp;
            }
        }
    }
}

// ---------------------------------------------------------------------------
// K_loop_p: ONE persistent kernel, 63 iterations. grid (32 fg, 8 rg) x 256.
// EXACT round-0 structure AND round-0 __launch_bounds__(256) — the (256,1)
// variant made the cooperative launch fail silently (all-zeros output,
// rounds 1-3). Single change vs round-0: A-operand loads batched (ub[32])
// -> 1 L3 round trip instead of 8 serial load-use chains.
// ---------------------------------------------------------------------------
__global__ __launch_bounds__(256) void k_loop_p(const int* __restrict__ length,
                                                const float* __restrict__ b_comp,
                                                const float* __restrict__ q,
                                                float* __restrict__ out) {
    int fg = blockIdx.x, rg = blockIdx.y;
    int tid = threadIdx.x;
    int wv = tid >> 6, lane = tid & 63;
    int l15 = lane & 15, quad = lane >> 4;
    const float sqrt_h = 22.627416997969522f;

    __shared__ int s_next[8][64], s_prev[8][64], s_aliv[8][64];
    __shared__ int s_enc[8][64];    // slot -> enc (<64 leaf, 64+candrow)
    __shared__ int s_prow[8][64];   // left-slot -> cand row of its current pair
    __shared__ float s_score[8][64];
    __shared__ int s_np[8][2];
    __shared__ int s_dl[16], s_dr[16], s_dd[16];
    __shared__ int s_len[8];
    __shared__ float s_red[192][20]; // waves 1-3 partial acc (5 tiles x 4)

    // ---- init: each wave builds its own 2 batches ----
    for (int bl = wv * 2; bl < wv * 2 + 2; ++bl) {
        int b = rg * 8 + bl;
        int len = length[b];
        if (lane == 0) { s_len[bl] = len; s_np[bl][0] = -1; s_np[bl][1] = -1; }
        s_next[bl][lane] = (lane < len - 1) ? lane + 1 : -1;
        s_prev[bl][lane] = (lane > 0 && lane < len) ? lane - 1 : -1;
        s_aliv[bl][lane] = (lane < len) ? 1 : 0;
        s_enc[bl][lane] = lane;
        s_prow[bl][lane] = lane;
        float sc = -3.0e38f;
        if (lane < 63 && lane <= len - 2) {
            float s = 0.0f;
            for (int f = 0; f < 32; ++f) s += g_spinit[(size_t)(b * 63 + lane) * 32 + f];
            sc = s / sqrt_h;
        }
        s_score[bl][lane] = sc;
    }
    __syncthreads();

    int col = fg * 16 + l15;
    float bc[5];
#pragma unroll
    for (int g = 0; g < 5; ++g) bc[g] = b_comp[g * 512 + col];
    float qv = q[col];
    const bf16* wh = g_wchi + (size_t)col * 1024;
    const bf16* wl = g_wclo + (size_t)col * 1024;

    for (int it = 0; it < 63; ++it) {
        if (it > 0) {
            __builtin_amdgcn_s_waitcnt(0);   // drain own sc1 stores (wave0)
            __syncthreads();
            if (tid == 0) {
                int* bp = &g_bar[it * 128 + rg * 16];
                __hip_atomic_fetch_add(bp, 1, __ATOMIC_RELAXED, __HIP_MEMORY_SCOPE_AGENT);
                while (__hip_atomic_load(bp, __ATOMIC_RELAXED, __HIP_MEMORY_SCOPE_AGENT) < 32)
                    __builtin_amdgcn_s_sleep(2);
            }
            __syncthreads();
            __atomic_signal_fence(__ATOMIC_SEQ_CST);
        }
        // ------------- selection: wave w owns batches {2w, 2w+1} -----------
        for (int bl = wv * 2; bl < wv * 2 + 2; ++bl) {
            int len = s_len[bl];
            int r0 = bl * 2;
            bool active = (it <= len - 2);
            if (!active) {
                if (lane == 0) {
                    s_dl[r0] = 0; s_dr[r0] = 1; s_dd[r0] = -1;
                    s_dl[r0 + 1] = 0; s_dr[r0 + 1] = 1; s_dd[r0 + 1] = -1;
                }
                continue;
            }
            if (it > 0) {
                int s = lane >> 5, f = lane & 31;
                int p = s_np[bl][s];
                float v = (p >= 0)
                    ? ldaf(&g_spart[(((it - 1) & 1) * 128 + rg * 16 + r0 + s) * 32 + f])
                    : 0.0f;
#pragma unroll
                for (int off = 1; off < 32; off <<= 1) v += __shfl_xor(v, off, 32);
                if (f == 0 && p >= 0) s_score[bl][p] = v / sqrt_h;
            }
            float val = -3.0e38f;
            int idx = lane;
            if (lane < 63 && s_aliv[bl][lane] && s_next[bl][lane] >= 0)
                val = s_score[bl][lane];
#pragma unroll
            for (int off = 1; off < 64; off <<= 1) {
                float ov = __shfl_xor(val, off, 64);
                int oi = __shfl_xor(idx, off, 64);
                if (ov > val || (ov == val && oi < idx)) { val = ov; idx = oi; }
            }
            int a = idx;
            if (a < 0) a = 0;
            if (a > 62) a = 62;
            if (lane == 0) {
                int bn = s_next[bl][a];
                int nn = (bn >= 0) ? s_next[bl][bn] : -1;
                s_next[bl][a] = nn;
                if (nn >= 0) s_prev[bl][nn] = a;
                if (bn >= 0) s_aliv[bl][bn] = 0;
                s_enc[bl][a] = 64 + s_prow[bl][a];
                int pL = s_prev[bl][a];
                int pR = (nn >= 0) ? a : -1;
                s_np[bl][0] = pL;
                s_np[bl][1] = pR;
                if (pL >= 0) {
                    s_dl[r0] = s_enc[bl][pL]; s_dr[r0] = s_enc[bl][a];
                    s_dd[r0] = 63 + 2 * it;  s_prow[bl][pL] = 63 + 2 * it;
                } else { s_dl[r0] = 0; s_dr[r0] = 1; s_dd[r0] = -1; }
                if (pR >= 0) {
                    s_dl[r0 + 1] = s_enc[bl][a]; s_dr[r0 + 1] = s_enc[bl][nn];
                    s_dd[r0 + 1] = 63 + 2 * it + 1; s_prow[bl][a] = 63 + 2 * it + 1;
                } else { s_dl[r0 + 1] = 0; s_dr[r0 + 1] = 1; s_dd[r0 + 1] = -1; }
            }
        }
        __syncthreads();
        // ------------- GEMM: K split across 4 waves ------------------------
        if (it < 62) {
            int b_r = rg * 8 + (l15 >> 1);
            const unsigned* la = g_uhl + ((size_t)b_r * UROW + s_dl[l15]) * 512;
            const unsigned* ra = g_uhl + ((size_t)b_r * UROW + s_dr[l15]) * 512;
            const unsigned* base = (wv < 2) ? la : ra;   // kc<16 <=> k<512

            // CHANGE (a): batch ALL A loads -> one L3 round trip instead of 8
            u64 ub[32];
#pragma unroll
            for (int i = 0; i < 8; ++i) {
                int kk = ((wv * 8 + i) * 32 + quad * 8) & 511;
                const unsigned* ap = base + kk;
                ub[4 * i + 0] = lda64(ap);
                ub[4 * i + 1] = lda64(ap + 2);
                ub[4 * i + 2] = lda64(ap + 4);
                ub[4 * i + 3] = lda64(ap + 6);
            }
            f32x4 acc[5] = {};
#pragma unroll
            for (int i = 0; i < 8; ++i) {
                int k = (wv * 8 + i) * 32 + quad * 8;
                u64 u0 = ub[4 * i + 0], u1 = ub[4 * i + 1];
                u64 u2 = ub[4 * i + 2], u3 = ub[4 * i + 3];
                s16x8 aH, aL;
                aH[0] = (short)u0; aL[0] = (short)(u0 >> 16);
                aH[1] = (short)(u0 >> 32); aL[1] = (short)(u0 >> 48);
                aH[2] = (short)u1; aL[2] = (short)(u1 >> 16);
                aH[3] = (short)(u1 >> 32); aL[3] = (short)(u1 >> 48);
                aH[4] = (short)u2; aL[4] = (short)(u2 >> 16);
                aH[5] = (short)(u2 >> 32); aL[5] = (short)(u2 >> 48);
                aH[6] = (short)u3; aL[6] = (short)(u3 >> 16);
                aH[7] = (short)(u3 >> 32); aL[7] = (short)(u3 >> 48);
#pragma unroll
                for (int g = 0; g < 5; ++g) {
                    s16x8 bH = ld8(wh + (size_t)g * 512 * 1024 + k);
                    s16x8 bL = ld8(wl + (size_t)g * 512 * 1024 + k);
                    acc[g] = MFMA16(aH, bH, acc[g]);
                    acc[g] = MFMA16(aH, bL, acc[g]);
                    acc[g] = MFMA16(aL, bH, acc[g]);
                }
            }
            if (wv > 0) {
#pragma unroll
                for (int g = 0; g < 5; ++g)
#pragma unroll
                    for (int rr = 0; rr < 4; ++rr)
                        s_red[(wv - 1) * 64 + lane][g * 4 + rr] = acc[g][rr];
            }
            __syncthreads();
            if (wv == 0) {
                // deterministic reduction: w0 + w1 + w2 + w3
#pragma unroll
                for (int g = 0; g < 5; ++g)
#pragma unroll
                    for (int rr = 0; rr < 4; ++rr)
                        acc[g][rr] = ((acc[g][rr] + s_red[lane][g * 4 + rr])
                                      + s_red[64 + lane][g * 4 + rr])
                                     + s_red[128 + lane][g * 4 + rr];
                float cl[4], cr[4];
#pragma unroll
                for (int rr = 0; rr < 4; ++rr) {
                    int rowm = quad * 4 + rr;
                    int bb = rg * 8 + (rowm >> 1);
                    cl[rr] = ldaf(&g_uc[((size_t)bb * UROW + s_dl[rowm]) * 512 + col]);
                    cr[rr] = ldaf(&g_uc[((size_t)bb * UROW + s_dr[rowm]) * 512 + col]);
                }
#pragma unroll
                for (int rr = 0; rr < 4; ++rr) {
                    int rowm = quad * 4 + rr;
                    int bb = rg * 8 + (rowm >> 1);
                    int dest = s_dd[rowm];
                    float gi = acc[0][rr] + bc[0];
                    float fl = acc[1][rr] + bc[1];
                    float fr = acc[2][rr] + bc[2];
                    float gu = acc[3][rr] + bc[3];
                    float go = acc[4][rr] + bc[4];
                    float cn = cl[rr] * sigf(fl + 1.0f) + cr[rr] * sigf(fr + 1.0f)
                               + tanhf(gu) * sigf(gi);
                    float hn = sigf(go) * tanhf(cn);
                    float sp = hn * qv;
#pragma unroll
                    for (int off = 1; off < 16; off <<= 1) sp += __shfl_xor(sp, off, 16);
                    if (dest >= 0) {
                        size_t o = ((size_t)bb * UROW + 64 + dest) * 512 + col;
                        stau(&g_uhl[o], packhl(hn));
                        staf(&g_uc[o], cn);
                        g_candh[((size_t)bb * NROW + dest) * 512 + col] = hn;
                        if (l15 == 0)
                            staf(&g_spart[((it & 1) * 128 + rg * 16 + rowm) * 32 + fg], sp);
                    }
                }
            }
        }
        __syncthreads();
    }
    // ---------------- output: wave0, block-owned cols ----------------------
    if (wv == 0) {
        __builtin_amdgcn_s_waitcnt(0);
        for (int bl = 0; bl < 8; ++bl) {
            if ((lane >> 4) != (bl & 3)) continue;
            int b = rg * 8 + bl;
            int e0 = s_enc[bl][0];
            float hv, cv;
            if (e0 >= 64) {
                hv = g_candh[((size_t)b * NROW + e0 - 64) * 512 + col];
                cv = ldaf(&g_uc[((size_t)b * UROW + e0) * 512 + col]);
            } else {   // unreachable for len>=2, defensive
                unsigned u = g_uhl[((size_t)b * UROW + e0) * 512 + col];
                bf16 h0 = __builtin_bit_cast(bf16, (unsigned short)(u & 0xffff));
                bf16 l0 = __builtin_bit_cast(bf16, (unsigned short)(u >> 16));
                hv = (float)h0 + (float)l0;
                cv = ldaf(&g_uc[((size_t)b * UROW + e0) * 512 + col]);
            }
            out[(size_t)b * 512 + col] = hv;
            out[(size_t)(64 * 512) + b * 512 + col] = cv;
        }
    }
}

// ---------------------------------------------------------------------------
extern "C" void kernel_launch(void* const* d_in, const int* in_sizes, int n_in,
                              void* d_out, int out_size, void* d_ws, size_t ws_size,
                              hipStream_t stream) {
    const float* x = (const float*)d_in[0];
    const int* length = (const int*)d_in[1];
    const float* w_word = (const float*)d_in[2];
    const float* b_word = (const float*)d_in[3];
    const float* w_comp = (const float*)d_in[4];
    const float* b_comp = (const float*)d_in[5];
    const float* q = (const float*)d_in[6];
    float* out = (float*)d_out;

    int* barp;
    hipGetSymbolAddress((void**)&barp, HIP_SYMBOL(g_bar));
    hipMemsetAsync(barp, 0, 63 * 128 * sizeof(int), stream);

    hipLaunchKernelGGL(k_prep, dim3(2048), dim3(256), 0, stream, x, w_word, w_comp);
    hipLaunchKernelGGL(k_leaf, dim3(16, 256), dim3(64), 0, stream, b_word);
    hipLaunchKernelGGL(k_cells_init, dim3(32, 63), dim3(64), 0, stream,
                       length, b_comp, q);

    void* args[] = {(void*)&length, (void*)&b_comp, (void*)&q, (void*)&out};
    hipError_t ce = hipLaunchCooperativeKernel((void*)k_loop_p, dim3(32, 8),
                                               dim3(256), args, 0, stream);
    if (ce != hipSuccess) {
        // fallback: plain launch. 256 blocks on 256 CUs -> all co-resident;
        // the g_bar spin-barrier does not require the cooperative API.
        hipLaunchKernelGGL(k_loop_p, dim3(32, 8), dim3(256), 0, stream,
                           length, b_comp, q, out);
    }
}

// Round 5
// 1604.691 us; speedup vs baseline: 1.1540x; 1.0809x over previous
//
#include <hip/hip_runtime.h>

typedef __bf16 bf16;
typedef short s16x8 __attribute__((ext_vector_type(8)));
typedef float f32x4 __attribute__((ext_vector_type(4)));
typedef unsigned long long u64;

#define MFMA16(a, b, c) __builtin_amdgcn_mfma_f32_16x16x32_bf16((a), (b), (c), 0, 0, 0)
#define NROW 187   // cand rows per batch: 63 init + 2/iter
#define UROW 251   // unified rows: 64 leaf + 187 cand

__device__ __forceinline__ float sigf(float x) { return 1.0f / (1.0f + expf(-x)); }
__device__ __forceinline__ s16x8 ld8(const bf16* p) { return *(const s16x8*)p; }

__device__ __forceinline__ unsigned packhl(float v) {
    bf16 h = (bf16)v;
    bf16 l = (bf16)(v - (float)h);
    return (unsigned)__builtin_bit_cast(unsigned short, h) |
           ((unsigned)__builtin_bit_cast(unsigned short, l) << 16);
}
__device__ __forceinline__ u64 lda64(const unsigned* p) {
    return __hip_atomic_load((const u64*)p, __ATOMIC_RELAXED, __HIP_MEMORY_SCOPE_AGENT);
}
__device__ __forceinline__ float ldaf(const float* p) {
    return __hip_atomic_load(p, __ATOMIC_RELAXED, __HIP_MEMORY_SCOPE_AGENT);
}
__device__ __forceinline__ void staf(float* p, float v) {
    __hip_atomic_store(p, v, __ATOMIC_RELAXED, __HIP_MEMORY_SCOPE_AGENT);
}
__device__ __forceinline__ void stau(unsigned* p, unsigned v) {
    __hip_atomic_store(p, v, __ATOMIC_RELAXED, __HIP_MEMORY_SCOPE_AGENT);
}

// ---------------- device-global workspace (fp32 in / fp32 out) -------------
__device__ bf16  g_xhi[64 * 64 * 512], g_xlo[64 * 64 * 512];
__device__ bf16  g_wwhi[1024 * 512], g_wwlo[1024 * 512];
__device__ bf16  g_wchi[2560 * 1024], g_wclo[2560 * 1024];
__device__ bf16  g_hhi[64 * 64 * 512];              // leaf h hi (k_cells_init A)
__device__ bf16  g_hlo[64 * 64 * 512];              // leaf h lo
__device__ unsigned g_uhl[(size_t)64 * UROW * 512]; // unified h packed (hi|lo<<16)
__device__ float g_uc[(size_t)64 * UROW * 512];     // unified c fp32
__device__ float g_candh[(size_t)64 * NROW * 512];  // cand h fp32 (self-read only)
__device__ float g_spinit[64 * 63 * 32];
__device__ float g_spart[2 * 128 * 32];             // [parity][rg*16+row][fg]
__device__ int   g_bar[63 * 128];                   // [it][rg*16]

// ---------------- prep: all three fp32 -> bf16 hi/lo splits ----------------
__global__ __launch_bounds__(256) void k_prep(const float* __restrict__ x,
                                              const float* __restrict__ ww,
                                              const float* __restrict__ wc) {
    const int NX = 64 * 64 * 512, NW = 1024 * 512, NC = 2560 * 1024;
    int stride = gridDim.x * 256, i0 = blockIdx.x * 256 + threadIdx.x;
    for (int i = i0; i < NX; i += stride) {
        float v = x[i];
        bf16 h = (bf16)v;
        g_xhi[i] = h;
        g_xlo[i] = (bf16)(v - (float)h);
    }
    for (int i = i0; i < NW; i += stride) {
        float v = ww[i];
        bf16 h = (bf16)v;
        g_wwhi[i] = h;
        g_wwlo[i] = (bf16)(v - (float)h);
    }
    for (int i = i0; i < NC; i += stride) {
        float v = wc[i];
        bf16 h = (bf16)v;
        g_wchi[i] = h;
        g_wclo[i] = (bf16)(v - (float)h);
    }
}

// ---------------------------------------------------------------------------
// K0: leaf projection (M=4096, N=1024, K=512), 3-pass hi/lo MFMA.
// ---------------------------------------------------------------------------
__global__ __launch_bounds__(64) void k_leaf(const float* __restrict__ b_word) {
    int cg = blockIdx.x, rg = blockIdx.y;
    int lane = threadIdx.x, l15 = lane & 15, quad = lane >> 4;
    const bf16* axh = g_xhi + (size_t)(rg * 16 + l15) * 512;
    const bf16* axl = g_xlo + (size_t)(rg * 16 + l15) * 512;
    const bf16* bwh = g_wwhi + (size_t)(cg * 64 + l15) * 512;
    const bf16* bwl = g_wwlo + (size_t)(cg * 64 + l15) * 512;
    f32x4 acc[4] = {};
    for (int kc = 0; kc < 16; ++kc) {
        int k = kc * 32 + quad * 8;
        s16x8 aH = ld8(axh + k), aL = ld8(axl + k);
#pragma unroll
        for (int t = 0; t < 4; ++t) {
            s16x8 bH = ld8(bwh + (size_t)t * 16 * 512 + k);
            s16x8 bL = ld8(bwl + (size_t)t * 16 * 512 + k);
            acc[t] = MFMA16(aH, bH, acc[t]);
            acc[t] = MFMA16(aH, bL, acc[t]);
            acc[t] = MFMA16(aL, bH, acc[t]);
        }
    }
#pragma unroll
    for (int t = 0; t < 4; ++t) {
        int col = cg * 64 + t * 16 + l15;
        float bw = b_word[col];
#pragma unroll
        for (int r = 0; r < 4; ++r) {
            int m = rg * 16 + quad * 4 + r;
            int bb = m >> 6, sl = m & 63;
            float v = acc[t][r] + bw;
            if (col < 512) {
                bf16 hi = (bf16)v;
                g_hhi[(size_t)m * 512 + col] = hi;
                g_hlo[(size_t)m * 512 + col] = (bf16)(v - (float)hi);
                g_uhl[((size_t)bb * UROW + sl) * 512 + col] = packhl(v);
            } else {
                g_uc[((size_t)bb * UROW + sl) * 512 + (col - 512)] = v;
            }
        }
    }
}

// ---------------------------------------------------------------------------
// K1: initial candidates, all pairs (b,j) -> unified rows 64..126.
// ---------------------------------------------------------------------------
__global__ __launch_bounds__(64) void k_cells_init(const int* __restrict__ length,
                                                   const float* __restrict__ b_comp,
                                                   const float* __restrict__ q) {
    int fg = blockIdx.x;            // 0..31
    int rg = blockIdx.y;            // 0..62
    int lane = threadIdx.x, l15 = lane & 15, quad = lane >> 4;

    const bf16 *ahi[4], *alo[4];
#pragma unroll
    for (int t = 0; t < 4; ++t) {
        int r = rg * 64 + t * 16 + l15;      // pair row 0..4031
        int b = r / 63, j = r - b * 63;
        ahi[t] = g_hhi + (size_t)(b * 64 + j) * 512;
        alo[t] = g_hlo + (size_t)(b * 64 + j) * 512;
    }
    const bf16* wh = g_wchi + (size_t)(fg * 16 + l15) * 1024;
    const bf16* wl = g_wclo + (size_t)(fg * 16 + l15) * 1024;
    f32x4 acc[4][5] = {};
    for (int kc = 0; kc < 32; ++kc) {
        int k = kc * 32 + quad * 8;
        int kk = k & 511;
        size_t sh = (k < 512) ? 0 : 512;     // row j vs j+1 (contiguous rows)
        s16x8 aH[4], aL[4];
#pragma unroll
        for (int t = 0; t < 4; ++t) {
            aH[t] = ld8(ahi[t] + sh + kk);
            aL[t] = ld8(alo[t] + sh + kk);
        }
#pragma unroll
        for (int g = 0; g < 5; ++g) {
            s16x8 bH = ld8(wh + (size_t)g * 512 * 1024 + k);
            s16x8 bL = ld8(wl + (size_t)g * 512 * 1024 + k);
#pragma unroll
            for (int t = 0; t < 4; ++t) {
                acc[t][g] = MFMA16(aH[t], bH, acc[t][g]);
                acc[t][g] = MFMA16(aH[t], bL, acc[t][g]);
                acc[t][g] = MFMA16(aL[t], bH, acc[t][g]);
            }
        }
    }
    int col = fg * 16 + l15;
    float bc[5];
#pragma unroll
    for (int g = 0; g < 5; ++g) bc[g] = b_comp[g * 512 + col];
    float qv = q[col];
#pragma unroll
    for (int t = 0; t < 4; ++t) {
#pragma unroll
        for (int rr = 0; rr < 4; ++rr) {
            int R = rg * 64 + t * 16 + quad * 4 + rr;
            int B_ = R / 63, J = R - B_ * 63;
            bool act = (J <= length[B_] - 2);
            float gi = acc[t][0][rr] + bc[0];
            float fl = acc[t][1][rr] + bc[1];
            float fr = acc[t][2][rr] + bc[2];
            float gu = acc[t][3][rr] + bc[3];
            float go = acc[t][4][rr] + bc[4];
            float cl = g_uc[((size_t)B_ * UROW + J) * 512 + col];
            float cr = g_uc[((size_t)B_ * UROW + J + 1) * 512 + col];
            float cn = cl * sigf(fl + 1.0f) + cr * sigf(fr + 1.0f) + tanhf(gu) * sigf(gi);
            float hn = sigf(go) * tanhf(cn);
            float sp = hn * qv;
#pragma unroll
            for (int off = 1; off < 16; off <<= 1) sp += __shfl_xor(sp, off, 16);
            if (act) {
                size_t o = ((size_t)B_ * UROW + 64 + J) * 512 + col;
                g_uhl[o] = packhl(hn);
                g_uc[o] = cn;
                g_candh[((size_t)B_ * NROW + J) * 512 + col] = hn;
                if (l15 == 0) g_spinit[(size_t)R * 32 + fg] = sp;
            }
        }
    }
}

// ---------------------------------------------------------------------------
// K_loop_p: ONE persistent kernel, 63 iterations. grid (32 fg, 8 rg) x 256.
// Round-4 base (batched A-loads, proven) + two audited changes:
//  (b) epilogue split across 4 waves (rowm = quad*4 + wv): LDS reduce,
//      cl/cr loads, transcendentals, global stores, and next-iter drain all
//      run 4-way parallel. Reduction order ((w0+w1)+w2)+w3 preserved.
//  (c) cl/cr prefetched before the MFMA loop (L3 latency under compute).
// __launch_bounds__(256) — NOT (256,1), which broke cooperative launch.
// ---------------------------------------------------------------------------
__global__ __launch_bounds__(256) void k_loop_p(const int* __restrict__ length,
                                                const float* __restrict__ b_comp,
                                                const float* __restrict__ q,
                                                float* __restrict__ out) {
    int fg = blockIdx.x, rg = blockIdx.y;
    int tid = threadIdx.x;
    int wv = tid >> 6, lane = tid & 63;
    int l15 = lane & 15, quad = lane >> 4;
    const float sqrt_h = 22.627416997969522f;

    __shared__ int s_next[8][64], s_prev[8][64], s_aliv[8][64];
    __shared__ int s_enc[8][64];    // slot -> enc (<64 leaf, 64+candrow)
    __shared__ int s_prow[8][64];   // left-slot -> cand row of its current pair
    __shared__ float s_score[8][64];
    __shared__ int s_np[8][2];
    __shared__ int s_dl[16], s_dr[16], s_dd[16];
    __shared__ int s_len[8];
    __shared__ float s_red[4][64][21]; // all 4 waves' partials (stride 21)

    // ---- init: each wave builds its own 2 batches ----
    for (int bl = wv * 2; bl < wv * 2 + 2; ++bl) {
        int b = rg * 8 + bl;
        int len = length[b];
        if (lane == 0) { s_len[bl] = len; s_np[bl][0] = -1; s_np[bl][1] = -1; }
        s_next[bl][lane] = (lane < len - 1) ? lane + 1 : -1;
        s_prev[bl][lane] = (lane > 0 && lane < len) ? lane - 1 : -1;
        s_aliv[bl][lane] = (lane < len) ? 1 : 0;
        s_enc[bl][lane] = lane;
        s_prow[bl][lane] = lane;
        float sc = -3.0e38f;
        if (lane < 63 && lane <= len - 2) {
            float s = 0.0f;
            for (int f = 0; f < 32; ++f) s += g_spinit[(size_t)(b * 63 + lane) * 32 + f];
            sc = s / sqrt_h;
        }
        s_score[bl][lane] = sc;
    }
    __syncthreads();

    int col = fg * 16 + l15;
    float bc[5];
#pragma unroll
    for (int g = 0; g < 5; ++g) bc[g] = b_comp[g * 512 + col];
    float qv = q[col];
    const bf16* wh = g_wchi + (size_t)col * 1024;
    const bf16* wl = g_wclo + (size_t)col * 1024;

    for (int it = 0; it < 63; ++it) {
        if (it > 0) {
            __builtin_amdgcn_s_waitcnt(0);   // drain own stores (each wave)
            __syncthreads();
            if (tid == 0) {
                int* bp = &g_bar[it * 128 + rg * 16];
                __hip_atomic_fetch_add(bp, 1, __ATOMIC_RELAXED, __HIP_MEMORY_SCOPE_AGENT);
                while (__hip_atomic_load(bp, __ATOMIC_RELAXED, __HIP_MEMORY_SCOPE_AGENT) < 32)
                    __builtin_amdgcn_s_sleep(2);
            }
            __syncthreads();
            __atomic_signal_fence(__ATOMIC_SEQ_CST);
        }
        // ------------- selection: wave w owns batches {2w, 2w+1} -----------
        for (int bl = wv * 2; bl < wv * 2 + 2; ++bl) {
            int len = s_len[bl];
            int r0 = bl * 2;
            bool active = (it <= len - 2);
            if (!active) {
                if (lane == 0) {
                    s_dl[r0] = 0; s_dr[r0] = 1; s_dd[r0] = -1;
                    s_dl[r0 + 1] = 0; s_dr[r0 + 1] = 1; s_dd[r0 + 1] = -1;
                }
                continue;
            }
            if (it > 0) {
                int s = lane >> 5, f = lane & 31;
                int p = s_np[bl][s];
                float v = (p >= 0)
                    ? ldaf(&g_spart[(((it - 1) & 1) * 128 + rg * 16 + r0 + s) * 32 + f])
                    : 0.0f;
#pragma unroll
                for (int off = 1; off < 32; off <<= 1) v += __shfl_xor(v, off, 32);
                if (f == 0 && p >= 0) s_score[bl][p] = v / sqrt_h;
            }
            float val = -3.0e38f;
            int idx = lane;
            if (lane < 63 && s_aliv[bl][lane] && s_next[bl][lane] >= 0)
                val = s_score[bl][lane];
#pragma unroll
            for (int off = 1; off < 64; off <<= 1) {
                float ov = __shfl_xor(val, off, 64);
                int oi = __shfl_xor(idx, off, 64);
                if (ov > val || (ov == val && oi < idx)) { val = ov; idx = oi; }
            }
            int a = idx;
            if (a < 0) a = 0;
            if (a > 62) a = 62;
            if (lane == 0) {
                int bn = s_next[bl][a];
                int nn = (bn >= 0) ? s_next[bl][bn] : -1;
                s_next[bl][a] = nn;
                if (nn >= 0) s_prev[bl][nn] = a;
                if (bn >= 0) s_aliv[bl][bn] = 0;
                s_enc[bl][a] = 64 + s_prow[bl][a];
                int pL = s_prev[bl][a];
                int pR = (nn >= 0) ? a : -1;
                s_np[bl][0] = pL;
                s_np[bl][1] = pR;
                if (pL >= 0) {
                    s_dl[r0] = s_enc[bl][pL]; s_dr[r0] = s_enc[bl][a];
                    s_dd[r0] = 63 + 2 * it;  s_prow[bl][pL] = 63 + 2 * it;
                } else { s_dl[r0] = 0; s_dr[r0] = 1; s_dd[r0] = -1; }
                if (pR >= 0) {
                    s_dl[r0 + 1] = s_enc[bl][a]; s_dr[r0 + 1] = s_enc[bl][nn];
                    s_dd[r0 + 1] = 63 + 2 * it + 1; s_prow[bl][a] = 63 + 2 * it + 1;
                } else { s_dl[r0 + 1] = 0; s_dr[r0 + 1] = 1; s_dd[r0 + 1] = -1; }
            }
        }
        __syncthreads();
        // ------------- GEMM: K split across 4 waves ------------------------
        if (it < 62) {
            int b_r = rg * 8 + (l15 >> 1);
            const unsigned* la = g_uhl + ((size_t)b_r * UROW + s_dl[l15]) * 512;
            const unsigned* ra = g_uhl + ((size_t)b_r * UROW + s_dr[l15]) * 512;
            const unsigned* base = (wv < 2) ? la : ra;   // kc<16 <=> k<512

            // (a) batch ALL A loads -> one L3 round trip instead of 8
            u64 ub[32];
#pragma unroll
            for (int i = 0; i < 8; ++i) {
                int kk = ((wv * 8 + i) * 32 + quad * 8) & 511;
                const unsigned* ap = base + kk;
                ub[4 * i + 0] = lda64(ap);
                ub[4 * i + 1] = lda64(ap + 2);
                ub[4 * i + 2] = lda64(ap + 4);
                ub[4 * i + 3] = lda64(ap + 6);
            }
            // (c) prefetch epilogue cl/cr for this wave's row (rowm = quad*4+wv)
            int rowm = quad * 4 + wv;
            int bb = rg * 8 + (rowm >> 1);
            float clv = ldaf(&g_uc[((size_t)bb * UROW + s_dl[rowm]) * 512 + col]);
            float crv = ldaf(&g_uc[((size_t)bb * UROW + s_dr[rowm]) * 512 + col]);

            f32x4 acc[5] = {};
#pragma unroll
            for (int i = 0; i < 8; ++i) {
                int k = (wv * 8 + i) * 32 + quad * 8;
                u64 u0 = ub[4 * i + 0], u1 = ub[4 * i + 1];
                u64 u2 = ub[4 * i + 2], u3 = ub[4 * i + 3];
                s16x8 aH, aL;
                aH[0] = (short)u0; aL[0] = (short)(u0 >> 16);
                aH[1] = (short)(u0 >> 32); aL[1] = (short)(u0 >> 48);
                aH[2] = (short)u1; aL[2] = (short)(u1 >> 16);
                aH[3] = (short)(u1 >> 32); aL[3] = (short)(u1 >> 48);
                aH[4] = (short)u2; aL[4] = (short)(u2 >> 16);
                aH[5] = (short)(u2 >> 32); aL[5] = (short)(u2 >> 48);
                aH[6] = (short)u3; aL[6] = (short)(u3 >> 16);
                aH[7] = (short)(u3 >> 32); aL[7] = (short)(u3 >> 48);
#pragma unroll
                for (int g = 0; g < 5; ++g) {
                    s16x8 bH = ld8(wh + (size_t)g * 512 * 1024 + k);
                    s16x8 bL = ld8(wl + (size_t)g * 512 * 1024 + k);
                    acc[g] = MFMA16(aH, bH, acc[g]);
                    acc[g] = MFMA16(aH, bL, acc[g]);
                    acc[g] = MFMA16(aL, bH, acc[g]);
                }
            }
            // (b) all waves publish partials; wave w reduces + finishes rr=w
#pragma unroll
            for (int g = 0; g < 5; ++g)
#pragma unroll
                for (int rr = 0; rr < 4; ++rr)
                    s_red[wv][lane][g * 4 + rr] = acc[g][rr];
            __syncthreads();
            {
                float accs[5];
#pragma unroll
                for (int g = 0; g < 5; ++g)
                    accs[g] = ((s_red[0][lane][g * 4 + wv] + s_red[1][lane][g * 4 + wv])
                               + s_red[2][lane][g * 4 + wv]) + s_red[3][lane][g * 4 + wv];
                int dest = s_dd[rowm];
                float gi = accs[0] + bc[0];
                float fl = accs[1] + bc[1];
                float fr = accs[2] + bc[2];
                float gu = accs[3] + bc[3];
                float go = accs[4] + bc[4];
                float cn = clv * sigf(fl + 1.0f) + crv * sigf(fr + 1.0f)
                           + tanhf(gu) * sigf(gi);
                float hn = sigf(go) * tanhf(cn);
                float sp = hn * qv;
#pragma unroll
                for (int off = 1; off < 16; off <<= 1) sp += __shfl_xor(sp, off, 16);
                if (dest >= 0) {
                    size_t o = ((size_t)bb * UROW + 64 + dest) * 512 + col;
                    stau(&g_uhl[o], packhl(hn));
                    staf(&g_uc[o], cn);
                    g_candh[((size_t)bb * NROW + dest) * 512 + col] = hn;
                    if (l15 == 0)
                        staf(&g_spart[((it & 1) * 128 + rg * 16 + rowm) * 32 + fg], sp);
                }
            }
        }
        __syncthreads();
    }
    // ---------------- output: wave0, block-owned cols ----------------------
    if (wv == 0) {
        __builtin_amdgcn_s_waitcnt(0);
        for (int bl = 0; bl < 8; ++bl) {
            if ((lane >> 4) != (bl & 3)) continue;
            int b = rg * 8 + bl;
            int e0 = s_enc[bl][0];
            float hv, cv;
            if (e0 >= 64) {
                hv = g_candh[((size_t)b * NROW + e0 - 64) * 512 + col];
                cv = ldaf(&g_uc[((size_t)b * UROW + e0) * 512 + col]);
            } else {   // unreachable for len>=2, defensive
                unsigned u = g_uhl[((size_t)b * UROW + e0) * 512 + col];
                bf16 h0 = __builtin_bit_cast(bf16, (unsigned short)(u & 0xffff));
                bf16 l0 = __builtin_bit_cast(bf16, (unsigned short)(u >> 16));
                hv = (float)h0 + (float)l0;
                cv = ldaf(&g_uc[((size_t)b * UROW + e0) * 512 + col]);
            }
            out[(size_t)b * 512 + col] = hv;
            out[(size_t)(64 * 512) + b * 512 + col] = cv;
        }
    }
}

// ---------------------------------------------------------------------------
extern "C" void kernel_launch(void* const* d_in, const int* in_sizes, int n_in,
                              void* d_out, int out_size, void* d_ws, size_t ws_size,
                              hipStream_t stream) {
    const float* x = (const float*)d_in[0];
    const int* length = (const int*)d_in[1];
    const float* w_word = (const float*)d_in[2];
    const float* b_word = (const float*)d_in[3];
    const float* w_comp = (const float*)d_in[4];
    const float* b_comp = (const float*)d_in[5];
    const float* q = (const float*)d_in[6];
    float* out = (float*)d_out;

    int* barp;
    hipGetSymbolAddress((void**)&barp, HIP_SYMBOL(g_bar));
    hipMemsetAsync(barp, 0, 63 * 128 * sizeof(int), stream);

    hipLaunchKernelGGL(k_prep, dim3(2048), dim3(256), 0, stream, x, w_word, w_comp);
    hipLaunchKernelGGL(k_leaf, dim3(16, 256), dim3(64), 0, stream, b_word);
    hipLaunchKernelGGL(k_cells_init, dim3(32, 63), dim3(64), 0, stream,
                       length, b_comp, q);

    void* args[] = {(void*)&length, (void*)&b_comp, (void*)&q, (void*)&out};
    hipError_t ce = hipLaunchCooperativeKernel((void*)k_loop_p, dim3(32, 8),
                                               dim3(256), args, 0, stream);
    if (ce != hipSuccess) {
        // fallback: plain launch. 256 blocks on 256 CUs -> all co-resident;
        // the g_bar spin-barrier does not require the cooperative API.
        hipLaunchKernelGGL(k_loop_p, dim3(32, 8), dim3(256), 0, stream,
                           length, b_comp, q, out);
    }
}

// Round 6
// 1543.628 us; speedup vs baseline: 1.1996x; 1.0396x over previous
//
#include <hip/hip_runtime.h>

typedef __bf16 bf16;
typedef short s16x8 __attribute__((ext_vector_type(8)));
typedef float f32x4 __attribute__((ext_vector_type(4)));
typedef unsigned long long u64;

#define MFMA16(a, b, c) __builtin_amdgcn_mfma_f32_16x16x32_bf16((a), (b), (c), 0, 0, 0)
#define NROW 187   // cand rows per batch: 63 init + 2/iter
#define UROW 251   // unified rows: 64 leaf + 187 cand

__device__ __forceinline__ float sigf(float x) { return 1.0f / (1.0f + expf(-x)); }
__device__ __forceinline__ s16x8 ld8(const bf16* p) { return *(const s16x8*)p; }

__device__ __forceinline__ unsigned packhl(float v) {
    bf16 h = (bf16)v;
    bf16 l = (bf16)(v - (float)h);
    return (unsigned)__builtin_bit_cast(unsigned short, h) |
           ((unsigned)__builtin_bit_cast(unsigned short, l) << 16);
}
__device__ __forceinline__ u64 lda64(const unsigned* p) {
    return __hip_atomic_load((const u64*)p, __ATOMIC_RELAXED, __HIP_MEMORY_SCOPE_AGENT);
}
__device__ __forceinline__ unsigned lda32(const unsigned* p) {
    return __hip_atomic_load(p, __ATOMIC_RELAXED, __HIP_MEMORY_SCOPE_AGENT);
}
__device__ __forceinline__ float ldaf(const float* p) {
    return __hip_atomic_load(p, __ATOMIC_RELAXED, __HIP_MEMORY_SCOPE_AGENT);
}
__device__ __forceinline__ void staf(float* p, float v) {
    __hip_atomic_store(p, v, __ATOMIC_RELAXED, __HIP_MEMORY_SCOPE_AGENT);
}
__device__ __forceinline__ void stau(unsigned* p, unsigned v) {
    __hip_atomic_store(p, v, __ATOMIC_RELAXED, __HIP_MEMORY_SCOPE_AGENT);
}

// ---------------- device-global workspace (fp32 in / fp32 out) -------------
__device__ bf16  g_xhi[64 * 64 * 512], g_xlo[64 * 64 * 512];
__device__ bf16  g_wwhi[1024 * 512], g_wwlo[1024 * 512];
__device__ bf16  g_wchi[2560 * 1024], g_wclo[2560 * 1024];
__device__ bf16  g_hhi[64 * 64 * 512];              // leaf h hi (k_cells_init A)
__device__ bf16  g_hlo[64 * 64 * 512];              // leaf h lo
__device__ unsigned g_uhl[(size_t)64 * UROW * 512]; // unified h packed (hi|lo<<16)
__device__ float g_uc[(size_t)64 * UROW * 512];     // unified c fp32
__device__ float g_candh[(size_t)64 * NROW * 512];  // cand h fp32 (self-read only)
__device__ float g_spinit[64 * 63 * 32];
__device__ float g_spart[2 * 128 * 32];             // [parity][rg*16+row][fg]
__device__ unsigned g_flag[63 * 8 * 32];            // [it][rg][fg] ready flags

// ---------------- prep: all three fp32 -> bf16 hi/lo splits ----------------
__global__ __launch_bounds__(256) void k_prep(const float* __restrict__ x,
                                              const float* __restrict__ ww,
                                              const float* __restrict__ wc) {
    const int NX = 64 * 64 * 512, NW = 1024 * 512, NC = 2560 * 1024;
    int stride = gridDim.x * 256, i0 = blockIdx.x * 256 + threadIdx.x;
    for (int i = i0; i < NX; i += stride) {
        float v = x[i];
        bf16 h = (bf16)v;
        g_xhi[i] = h;
        g_xlo[i] = (bf16)(v - (float)h);
    }
    for (int i = i0; i < NW; i += stride) {
        float v = ww[i];
        bf16 h = (bf16)v;
        g_wwhi[i] = h;
        g_wwlo[i] = (bf16)(v - (float)h);
    }
    for (int i = i0; i < NC; i += stride) {
        float v = wc[i];
        bf16 h = (bf16)v;
        g_wchi[i] = h;
        g_wclo[i] = (bf16)(v - (float)h);
    }
}

// ---------------------------------------------------------------------------
// K0: leaf projection (M=4096, N=1024, K=512), 3-pass hi/lo MFMA.
// ---------------------------------------------------------------------------
__global__ __launch_bounds__(64) void k_leaf(const float* __restrict__ b_word) {
    int cg = blockIdx.x, rg = blockIdx.y;
    int lane = threadIdx.x, l15 = lane & 15, quad = lane >> 4;
    const bf16* axh = g_xhi + (size_t)(rg * 16 + l15) * 512;
    const bf16* axl = g_xlo + (size_t)(rg * 16 + l15) * 512;
    const bf16* bwh = g_wwhi + (size_t)(cg * 64 + l15) * 512;
    const bf16* bwl = g_wwlo + (size_t)(cg * 64 + l15) * 512;
    f32x4 acc[4] = {};
    for (int kc = 0; kc < 16; ++kc) {
        int k = kc * 32 + quad * 8;
        s16x8 aH = ld8(axh + k), aL = ld8(axl + k);
#pragma unroll
        for (int t = 0; t < 4; ++t) {
            s16x8 bH = ld8(bwh + (size_t)t * 16 * 512 + k);
            s16x8 bL = ld8(bwl + (size_t)t * 16 * 512 + k);
            acc[t] = MFMA16(aH, bH, acc[t]);
            acc[t] = MFMA16(aH, bL, acc[t]);
            acc[t] = MFMA16(aL, bH, acc[t]);
        }
    }
#pragma unroll
    for (int t = 0; t < 4; ++t) {
        int col = cg * 64 + t * 16 + l15;
        float bw = b_word[col];
#pragma unroll
        for (int r = 0; r < 4; ++r) {
            int m = rg * 16 + quad * 4 + r;
            int bb = m >> 6, sl = m & 63;
            float v = acc[t][r] + bw;
            if (col < 512) {
                bf16 hi = (bf16)v;
                g_hhi[(size_t)m * 512 + col] = hi;
                g_hlo[(size_t)m * 512 + col] = (bf16)(v - (float)hi);
                g_uhl[((size_t)bb * UROW + sl) * 512 + col] = packhl(v);
            } else {
                g_uc[((size_t)bb * UROW + sl) * 512 + (col - 512)] = v;
            }
        }
    }
}

// ---------------------------------------------------------------------------
// K1: initial candidates, all pairs (b,j) -> unified rows 64..126.
// ---------------------------------------------------------------------------
__global__ __launch_bounds__(64) void k_cells_init(const int* __restrict__ length,
                                                   const float* __restrict__ b_comp,
                                                   const float* __restrict__ q) {
    int fg = blockIdx.x;            // 0..31
    int rg = blockIdx.y;            // 0..62
    int lane = threadIdx.x, l15 = lane & 15, quad = lane >> 4;

    const bf16 *ahi[4], *alo[4];
#pragma unroll
    for (int t = 0; t < 4; ++t) {
        int r = rg * 64 + t * 16 + l15;      // pair row 0..4031
        int b = r / 63, j = r - b * 63;
        ahi[t] = g_hhi + (size_t)(b * 64 + j) * 512;
        alo[t] = g_hlo + (size_t)(b * 64 + j) * 512;
    }
    const bf16* wh = g_wchi + (size_t)(fg * 16 + l15) * 1024;
    const bf16* wl = g_wclo + (size_t)(fg * 16 + l15) * 1024;
    f32x4 acc[4][5] = {};
    for (int kc = 0; kc < 32; ++kc) {
        int k = kc * 32 + quad * 8;
        int kk = k & 511;
        size_t sh = (k < 512) ? 0 : 512;     // row j vs j+1 (contiguous rows)
        s16x8 aH[4], aL[4];
#pragma unroll
        for (int t = 0; t < 4; ++t) {
            aH[t] = ld8(ahi[t] + sh + kk);
            aL[t] = ld8(alo[t] + sh + kk);
        }
#pragma unroll
        for (int g = 0; g < 5; ++g) {
            s16x8 bH = ld8(wh + (size_t)g * 512 * 1024 + k);
            s16x8 bL = ld8(wl + (size_t)g * 512 * 1024 + k);
#pragma unroll
            for (int t = 0; t < 4; ++t) {
                acc[t][g] = MFMA16(aH[t], bH, acc[t][g]);
                acc[t][g] = MFMA16(aH[t], bL, acc[t][g]);
                acc[t][g] = MFMA16(aL[t], bH, acc[t][g]);
            }
        }
    }
    int col = fg * 16 + l15;
    float bc[5];
#pragma unroll
    for (int g = 0; g < 5; ++g) bc[g] = b_comp[g * 512 + col];
    float qv = q[col];
#pragma unroll
    for (int t = 0; t < 4; ++t) {
#pragma unroll
        for (int rr = 0; rr < 4; ++rr) {
            int R = rg * 64 + t * 16 + quad * 4 + rr;
            int B_ = R / 63, J = R - B_ * 63;
            bool act = (J <= length[B_] - 2);
            float gi = acc[t][0][rr] + bc[0];
            float fl = acc[t][1][rr] + bc[1];
            float fr = acc[t][2][rr] + bc[2];
            float gu = acc[t][3][rr] + bc[3];
            float go = acc[t][4][rr] + bc[4];
            float cl = g_uc[((size_t)B_ * UROW + J) * 512 + col];
            float cr = g_uc[((size_t)B_ * UROW + J + 1) * 512 + col];
            float cn = cl * sigf(fl + 1.0f) + cr * sigf(fr + 1.0f) + tanhf(gu) * sigf(gi);
            float hn = sigf(go) * tanhf(cn);
            float sp = hn * qv;
#pragma unroll
            for (int off = 1; off < 16; off <<= 1) sp += __shfl_xor(sp, off, 16);
            if (act) {
                size_t o = ((size_t)B_ * UROW + 64 + J) * 512 + col;
                g_uhl[o] = packhl(hn);
                g_uc[o] = cn;
                g_candh[((size_t)B_ * NROW + J) * 512 + col] = hn;
                if (l15 == 0) g_spinit[(size_t)R * 32 + fg] = sp;
            }
        }
    }
}

// ---------------------------------------------------------------------------
// K_loop_p: ONE persistent kernel, 63 iterations. grid (32 fg, 8 rg) x 256.
// Round-5 base (batched A-loads, 4-wave epilogue, cl/cr prefetch) + ONE
// change: the 32-way fetch_add counter barrier is replaced by a flag array
// (producer: drain + syncthreads + tid0 flag store; consumer: one coalesced
// 32-flag poll). Removes the serialized same-line RMW chain across 8 XCDs.
// Ordering is identical to the proven structure: all data stores drained
// (per-wave waitcnt(0)) before the __syncthreads that precedes the flag
// store, and consumers fence + read via agent-scope (L1-bypassing) atomics.
// __launch_bounds__(256) — NOT (256,1), which broke cooperative launch.
// ---------------------------------------------------------------------------
__global__ __launch_bounds__(256) void k_loop_p(const int* __restrict__ length,
                                                const float* __restrict__ b_comp,
                                                const float* __restrict__ q,
                                                float* __restrict__ out) {
    int fg = blockIdx.x, rg = blockIdx.y;
    int tid = threadIdx.x;
    int wv = tid >> 6, lane = tid & 63;
    int l15 = lane & 15, quad = lane >> 4;
    const float sqrt_h = 22.627416997969522f;

    __shared__ int s_next[8][64], s_prev[8][64], s_aliv[8][64];
    __shared__ int s_enc[8][64];    // slot -> enc (<64 leaf, 64+candrow)
    __shared__ int s_prow[8][64];   // left-slot -> cand row of its current pair
    __shared__ float s_score[8][64];
    __shared__ int s_np[8][2];
    __shared__ int s_dl[16], s_dr[16], s_dd[16];
    __shared__ int s_len[8];
    __shared__ float s_red[4][64][21]; // all 4 waves' partials (stride 21)

    // ---- init: each wave builds its own 2 batches ----
    for (int bl = wv * 2; bl < wv * 2 + 2; ++bl) {
        int b = rg * 8 + bl;
        int len = length[b];
        if (lane == 0) { s_len[bl] = len; s_np[bl][0] = -1; s_np[bl][1] = -1; }
        s_next[bl][lane] = (lane < len - 1) ? lane + 1 : -1;
        s_prev[bl][lane] = (lane > 0 && lane < len) ? lane - 1 : -1;
        s_aliv[bl][lane] = (lane < len) ? 1 : 0;
        s_enc[bl][lane] = lane;
        s_prow[bl][lane] = lane;
        float sc = -3.0e38f;
        if (lane < 63 && lane <= len - 2) {
            float s = 0.0f;
            for (int f = 0; f < 32; ++f) s += g_spinit[(size_t)(b * 63 + lane) * 32 + f];
            sc = s / sqrt_h;
        }
        s_score[bl][lane] = sc;
    }
    __syncthreads();

    int col = fg * 16 + l15;
    float bc[5];
#pragma unroll
    for (int g = 0; g < 5; ++g) bc[g] = b_comp[g * 512 + col];
    float qv = q[col];
    const bf16* wh = g_wchi + (size_t)col * 1024;
    const bf16* wl = g_wclo + (size_t)col * 1024;

    for (int it = 0; it < 63; ++it) {
        if (it > 0) {
            // flag-array barrier: wave0 polls all 32 fg producers of it-1
            if (wv == 0) {
                const unsigned* fp = &g_flag[((size_t)(it - 1) * 8 + rg) * 32];
                for (;;) {
                    unsigned f = lda32(fp + (lane & 31));
                    if (__all(f != 0)) break;
                    __builtin_amdgcn_s_sleep(1);
                }
            }
            __syncthreads();
            __atomic_signal_fence(__ATOMIC_SEQ_CST);
        }
        // ------------- selection: wave w owns batches {2w, 2w+1} -----------
        for (int bl = wv * 2; bl < wv * 2 + 2; ++bl) {
            int len = s_len[bl];
            int r0 = bl * 2;
            bool active = (it <= len - 2);
            if (!active) {
                if (lane == 0) {
                    s_dl[r0] = 0; s_dr[r0] = 1; s_dd[r0] = -1;
                    s_dl[r0 + 1] = 0; s_dr[r0 + 1] = 1; s_dd[r0 + 1] = -1;
                }
                continue;
            }
            if (it > 0) {
                int s = lane >> 5, f = lane & 31;
                int p = s_np[bl][s];
                float v = (p >= 0)
                    ? ldaf(&g_spart[(((it - 1) & 1) * 128 + rg * 16 + r0 + s) * 32 + f])
                    : 0.0f;
#pragma unroll
                for (int off = 1; off < 32; off <<= 1) v += __shfl_xor(v, off, 32);
                if (f == 0 && p >= 0) s_score[bl][p] = v / sqrt_h;
            }
            float val = -3.0e38f;
            int idx = lane;
            if (lane < 63 && s_aliv[bl][lane] && s_next[bl][lane] >= 0)
                val = s_score[bl][lane];
#pragma unroll
            for (int off = 1; off < 64; off <<= 1) {
                float ov = __shfl_xor(val, off, 64);
                int oi = __shfl_xor(idx, off, 64);
                if (ov > val || (ov == val && oi < idx)) { val = ov; idx = oi; }
            }
            int a = idx;
            if (a < 0) a = 0;
            if (a > 62) a = 62;
            if (lane == 0) {
                int bn = s_next[bl][a];
                int nn = (bn >= 0) ? s_next[bl][bn] : -1;
                s_next[bl][a] = nn;
                if (nn >= 0) s_prev[bl][nn] = a;
                if (bn >= 0) s_aliv[bl][bn] = 0;
                s_enc[bl][a] = 64 + s_prow[bl][a];
                int pL = s_prev[bl][a];
                int pR = (nn >= 0) ? a : -1;
                s_np[bl][0] = pL;
                s_np[bl][1] = pR;
                if (pL >= 0) {
                    s_dl[r0] = s_enc[bl][pL]; s_dr[r0] = s_enc[bl][a];
                    s_dd[r0] = 63 + 2 * it;  s_prow[bl][pL] = 63 + 2 * it;
                } else { s_dl[r0] = 0; s_dr[r0] = 1; s_dd[r0] = -1; }
                if (pR >= 0) {
                    s_dl[r0 + 1] = s_enc[bl][a]; s_dr[r0 + 1] = s_enc[bl][nn];
                    s_dd[r0 + 1] = 63 + 2 * it + 1; s_prow[bl][a] = 63 + 2 * it + 1;
                } else { s_dl[r0 + 1] = 0; s_dr[r0 + 1] = 1; s_dd[r0 + 1] = -1; }
            }
        }
        __syncthreads();
        // ------------- GEMM: K split across 4 waves ------------------------
        if (it < 62) {
            int b_r = rg * 8 + (l15 >> 1);
            const unsigned* la = g_uhl + ((size_t)b_r * UROW + s_dl[l15]) * 512;
            const unsigned* ra = g_uhl + ((size_t)b_r * UROW + s_dr[l15]) * 512;
            const unsigned* base = (wv < 2) ? la : ra;   // kc<16 <=> k<512

            // (a) batch ALL A loads -> one L3 round trip instead of 8
            u64 ub[32];
#pragma unroll
            for (int i = 0; i < 8; ++i) {
                int kk = ((wv * 8 + i) * 32 + quad * 8) & 511;
                const unsigned* ap = base + kk;
                ub[4 * i + 0] = lda64(ap);
                ub[4 * i + 1] = lda64(ap + 2);
                ub[4 * i + 2] = lda64(ap + 4);
                ub[4 * i + 3] = lda64(ap + 6);
            }
            // (c) prefetch epilogue cl/cr for this wave's row (rowm = quad*4+wv)
            int rowm = quad * 4 + wv;
            int bb = rg * 8 + (rowm >> 1);
            float clv = ldaf(&g_uc[((size_t)bb * UROW + s_dl[rowm]) * 512 + col]);
            float crv = ldaf(&g_uc[((size_t)bb * UROW + s_dr[rowm]) * 512 + col]);

            f32x4 acc[5] = {};
#pragma unroll
            for (int i = 0; i < 8; ++i) {
                int k = (wv * 8 + i) * 32 + quad * 8;
                u64 u0 = ub[4 * i + 0], u1 = ub[4 * i + 1];
                u64 u2 = ub[4 * i + 2], u3 = ub[4 * i + 3];
                s16x8 aH, aL;
                aH[0] = (short)u0; aL[0] = (short)(u0 >> 16);
                aH[1] = (short)(u0 >> 32); aL[1] = (short)(u0 >> 48);
                aH[2] = (short)u1; aL[2] = (short)(u1 >> 16);
                aH[3] = (short)(u1 >> 32); aL[3] = (short)(u1 >> 48);
                aH[4] = (short)u2; aL[4] = (short)(u2 >> 16);
                aH[5] = (short)(u2 >> 32); aL[5] = (short)(u2 >> 48);
                aH[6] = (short)u3; aL[6] = (short)(u3 >> 16);
                aH[7] = (short)(u3 >> 32); aL[7] = (short)(u3 >> 48);
#pragma unroll
                for (int g = 0; g < 5; ++g) {
                    s16x8 bH = ld8(wh + (size_t)g * 512 * 1024 + k);
                    s16x8 bL = ld8(wl + (size_t)g * 512 * 1024 + k);
                    acc[g] = MFMA16(aH, bH, acc[g]);
                    acc[g] = MFMA16(aH, bL, acc[g]);
                    acc[g] = MFMA16(aL, bH, acc[g]);
                }
            }
            // (b) all waves publish partials; wave w reduces + finishes rr=w
#pragma unroll
            for (int g = 0; g < 5; ++g)
#pragma unroll
                for (int rr = 0; rr < 4; ++rr)
                    s_red[wv][lane][g * 4 + rr] = acc[g][rr];
            __syncthreads();
            {
                float accs[5];
#pragma unroll
                for (int g = 0; g < 5; ++g)
                    accs[g] = ((s_red[0][lane][g * 4 + wv] + s_red[1][lane][g * 4 + wv])
                               + s_red[2][lane][g * 4 + wv]) + s_red[3][lane][g * 4 + wv];
                int dest = s_dd[rowm];
                float gi = accs[0] + bc[0];
                float fl = accs[1] + bc[1];
                float fr = accs[2] + bc[2];
                float gu = accs[3] + bc[3];
                float go = accs[4] + bc[4];
                float cn = clv * sigf(fl + 1.0f) + crv * sigf(fr + 1.0f)
                           + tanhf(gu) * sigf(gi);
                float hn = sigf(go) * tanhf(cn);
                float sp = hn * qv;
#pragma unroll
                for (int off = 1; off < 16; off <<= 1) sp += __shfl_xor(sp, off, 16);
                if (dest >= 0) {
                    size_t o = ((size_t)bb * UROW + 64 + dest) * 512 + col;
                    stau(&g_uhl[o], packhl(hn));
                    staf(&g_uc[o], cn);
                    g_candh[((size_t)bb * NROW + dest) * 512 + col] = hn;
                    if (l15 == 0)
                        staf(&g_spart[((it & 1) * 128 + rg * 16 + rowm) * 32 + fg], sp);
                }
            }
            // producer side of the barrier: drain own stores, rendezvous,
            // then one flag store for this (it, rg, fg)
            __builtin_amdgcn_s_waitcnt(0);
            __syncthreads();
            if (tid == 0)
                stau(&g_flag[((size_t)it * 8 + rg) * 32 + fg], 1u);
        } else {
            __syncthreads();
        }
    }
    // ---------------- output: wave0, block-owned cols ----------------------
    if (wv == 0) {
        __builtin_amdgcn_s_waitcnt(0);
        for (int bl = 0; bl < 8; ++bl) {
            if ((lane >> 4) != (bl & 3)) continue;
            int b = rg * 8 + bl;
            int e0 = s_enc[bl][0];
            float hv, cv;
            if (e0 >= 64) {
                hv = g_candh[((size_t)b * NROW + e0 - 64) * 512 + col];
                cv = ldaf(&g_uc[((size_t)b * UROW + e0) * 512 + col]);
            } else {   // unreachable for len>=2, defensive
                unsigned u = g_uhl[((size_t)b * UROW + e0) * 512 + col];
                bf16 h0 = __builtin_bit_cast(bf16, (unsigned short)(u & 0xffff));
                bf16 l0 = __builtin_bit_cast(bf16, (unsigned short)(u >> 16));
                hv = (float)h0 + (float)l0;
                cv = ldaf(&g_uc[((size_t)b * UROW + e0) * 512 + col]);
            }
            out[(size_t)b * 512 + col] = hv;
            out[(size_t)(64 * 512) + b * 512 + col] = cv;
        }
    }
}

// ---------------------------------------------------------------------------
extern "C" void kernel_launch(void* const* d_in, const int* in_sizes, int n_in,
                              void* d_out, int out_size, void* d_ws, size_t ws_size,
                              hipStream_t stream) {
    const float* x = (const float*)d_in[0];
    const int* length = (const int*)d_in[1];
    const float* w_word = (const float*)d_in[2];
    const float* b_word = (const float*)d_in[3];
    const float* w_comp = (const float*)d_in[4];
    const float* b_comp = (const float*)d_in[5];
    const float* q = (const float*)d_in[6];
    float* out = (float*)d_out;

    unsigned* flagp;
    hipGetSymbolAddress((void**)&flagp, HIP_SYMBOL(g_flag));
    hipMemsetAsync(flagp, 0, 63 * 8 * 32 * sizeof(unsigned), stream);

    hipLaunchKernelGGL(k_prep, dim3(2048), dim3(256), 0, stream, x, w_word, w_comp);
    hipLaunchKernelGGL(k_leaf, dim3(16, 256), dim3(64), 0, stream, b_word);
    hipLaunchKernelGGL(k_cells_init, dim3(32, 63), dim3(64), 0, stream,
                       length, b_comp, q);

    void* args[] = {(void*)&length, (void*)&b_comp, (void*)&q, (void*)&out};
    hipError_t ce = hipLaunchCooperativeKernel((void*)k_loop_p, dim3(32, 8),
                                               dim3(256), args, 0, stream);
    if (ce != hipSuccess) {
        // fallback: plain launch. 256 blocks on 256 CUs -> all co-resident;
        // the g_flag spin-barrier does not require the cooperative API.
        hipLaunchKernelGGL(k_loop_p, dim3(32, 8), dim3(256), 0, stream,
                           length, b_comp, q, out);
    }
}

// Round 8
// 1462.332 us; speedup vs baseline: 1.2663x; 1.0556x over previous
//
#include <hip/hip_runtime.h>

typedef __bf16 bf16;
typedef short s16x8 __attribute__((ext_vector_type(8)));
typedef float f32x4 __attribute__((ext_vector_type(4)));
typedef unsigned long long u64;

#define MFMA16(a, b, c) __builtin_amdgcn_mfma_f32_16x16x32_bf16((a), (b), (c), 0, 0, 0)
#define NROW 187   // cand rows per batch: 63 init + 2/iter
#define UROW 251   // unified rows: 64 leaf + 187 cand

__device__ __forceinline__ float sigf(float x) { return 1.0f / (1.0f + expf(-x)); }
__device__ __forceinline__ s16x8 ld8(const bf16* p) { return *(const s16x8*)p; }

__device__ __forceinline__ unsigned packhl(float v) {
    bf16 h = (bf16)v;
    bf16 l = (bf16)(v - (float)h);
    return (unsigned)__builtin_bit_cast(unsigned short, h) |
           ((unsigned)__builtin_bit_cast(unsigned short, l) << 16);
}
__device__ __forceinline__ u64 lda64(const unsigned* p) {
    return __hip_atomic_load((const u64*)p, __ATOMIC_RELAXED, __HIP_MEMORY_SCOPE_AGENT);
}
__device__ __forceinline__ u64 lda64u(const u64* p) {
    return __hip_atomic_load(p, __ATOMIC_RELAXED, __HIP_MEMORY_SCOPE_AGENT);
}
__device__ __forceinline__ void stau64(u64* p, u64 v) {
    __hip_atomic_store(p, v, __ATOMIC_RELAXED, __HIP_MEMORY_SCOPE_AGENT);
}
__device__ __forceinline__ unsigned lda32(const unsigned* p) {
    return __hip_atomic_load(p, __ATOMIC_RELAXED, __HIP_MEMORY_SCOPE_AGENT);
}
__device__ __forceinline__ float ldaf(const float* p) {
    return __hip_atomic_load(p, __ATOMIC_RELAXED, __HIP_MEMORY_SCOPE_AGENT);
}
__device__ __forceinline__ void staf(float* p, float v) {
    __hip_atomic_store(p, v, __ATOMIC_RELAXED, __HIP_MEMORY_SCOPE_AGENT);
}
__device__ __forceinline__ void stau(unsigned* p, unsigned v) {
    __hip_atomic_store(p, v, __ATOMIC_RELAXED, __HIP_MEMORY_SCOPE_AGENT);
}

// ---------------- device-global workspace (fp32 in / fp32 out) -------------
__device__ bf16  g_xhi[64 * 64 * 512], g_xlo[64 * 64 * 512];
__device__ bf16  g_wwhi[1024 * 512], g_wwlo[1024 * 512];
__device__ bf16  g_wchi[2560 * 1024], g_wclo[2560 * 1024];
__device__ bf16  g_hhi[64 * 64 * 512];              // leaf h hi (k_cells_init A)
__device__ bf16  g_hlo[64 * 64 * 512];              // leaf h lo
__device__ unsigned g_uhl[(size_t)64 * UROW * 512]; // unified h packed (hi|lo<<16)
__device__ float g_uc[(size_t)64 * UROW * 512];     // unified c fp32
__device__ float g_candh[(size_t)64 * NROW * 512];  // cand h fp32 (self-read only)
__device__ float g_spinit[64 * 63 * 32];
__device__ u64   g_spart2[2 * 128 * 32];            // [parity][rg*16+row][fg]: tag<<32|sp
__device__ unsigned g_flag[63 * 8 * 32];            // [it][rg][fg] h/c ready flags

// ---------------- prep: all three fp32 -> bf16 hi/lo splits ----------------
__global__ __launch_bounds__(256) void k_prep(const float* __restrict__ x,
                                              const float* __restrict__ ww,
                                              const float* __restrict__ wc) {
    const int NX = 64 * 64 * 512, NW = 1024 * 512, NC = 2560 * 1024;
    int stride = gridDim.x * 256, i0 = blockIdx.x * 256 + threadIdx.x;
    for (int i = i0; i < NX; i += stride) {
        float v = x[i];
        bf16 h = (bf16)v;
        g_xhi[i] = h;
        g_xlo[i] = (bf16)(v - (float)h);
    }
    for (int i = i0; i < NW; i += stride) {
        float v = ww[i];
        bf16 h = (bf16)v;
        g_wwhi[i] = h;
        g_wwlo[i] = (bf16)(v - (float)h);
    }
    for (int i = i0; i < NC; i += stride) {
        float v = wc[i];
        bf16 h = (bf16)v;
        g_wchi[i] = h;
        g_wclo[i] = (bf16)(v - (float)h);
    }
}

// ---------------------------------------------------------------------------
// K0: leaf projection (M=4096, N=1024, K=512), 3-pass hi/lo MFMA.
// ---------------------------------------------------------------------------
__global__ __launch_bounds__(64) void k_leaf(const float* __restrict__ b_word) {
    int cg = blockIdx.x, rg = blockIdx.y;
    int lane = threadIdx.x, l15 = lane & 15, quad = lane >> 4;
    const bf16* axh = g_xhi + (size_t)(rg * 16 + l15) * 512;
    const bf16* axl = g_xlo + (size_t)(rg * 16 + l15) * 512;
    const bf16* bwh = g_wwhi + (size_t)(cg * 64 + l15) * 512;
    const bf16* bwl = g_wwlo + (size_t)(cg * 64 + l15) * 512;
    f32x4 acc[4] = {};
    for (int kc = 0; kc < 16; ++kc) {
        int k = kc * 32 + quad * 8;
        s16x8 aH = ld8(axh + k), aL = ld8(axl + k);
#pragma unroll
        for (int t = 0; t < 4; ++t) {
            s16x8 bH = ld8(bwh + (size_t)t * 16 * 512 + k);
            s16x8 bL = ld8(bwl + (size_t)t * 16 * 512 + k);
            acc[t] = MFMA16(aH, bH, acc[t]);
            acc[t] = MFMA16(aH, bL, acc[t]);
            acc[t] = MFMA16(aL, bH, acc[t]);
        }
    }
#pragma unroll
    for (int t = 0; t < 4; ++t) {
        int col = cg * 64 + t * 16 + l15;
        float bw = b_word[col];
#pragma unroll
        for (int r = 0; r < 4; ++r) {
            int m = rg * 16 + quad * 4 + r;
            int bb = m >> 6, sl = m & 63;
            float v = acc[t][r] + bw;
            if (col < 512) {
                bf16 hi = (bf16)v;
                g_hhi[(size_t)m * 512 + col] = hi;
                g_hlo[(size_t)m * 512 + col] = (bf16)(v - (float)hi);
                g_uhl[((size_t)bb * UROW + sl) * 512 + col] = packhl(v);
            } else {
                g_uc[((size_t)bb * UROW + sl) * 512 + (col - 512)] = v;
            }
        }
    }
}

// ---------------------------------------------------------------------------
// K1: initial candidates, all pairs (b,j) -> unified rows 64..126.
// ---------------------------------------------------------------------------
__global__ __launch_bounds__(64) void k_cells_init(const int* __restrict__ length,
                                                   const float* __restrict__ b_comp,
                                                   const float* __restrict__ q) {
    int fg = blockIdx.x;            // 0..31
    int rg = blockIdx.y;            // 0..62
    int lane = threadIdx.x, l15 = lane & 15, quad = lane >> 4;

    const bf16 *ahi[4], *alo[4];
#pragma unroll
    for (int t = 0; t < 4; ++t) {
        int r = rg * 64 + t * 16 + l15;      // pair row 0..4031
        int b = r / 63, j = r - b * 63;
        ahi[t] = g_hhi + (size_t)(b * 64 + j) * 512;
        alo[t] = g_hlo + (size_t)(b * 64 + j) * 512;
    }
    const bf16* wh = g_wchi + (size_t)(fg * 16 + l15) * 1024;
    const bf16* wl = g_wclo + (size_t)(fg * 16 + l15) * 1024;
    f32x4 acc[4][5] = {};
    for (int kc = 0; kc < 32; ++kc) {
        int k = kc * 32 + quad * 8;
        int kk = k & 511;
        size_t sh = (k < 512) ? 0 : 512;     // row j vs j+1 (contiguous rows)
        s16x8 aH[4], aL[4];
#pragma unroll
        for (int t = 0; t < 4; ++t) {
            aH[t] = ld8(ahi[t] + sh + kk);
            aL[t] = ld8(alo[t] + sh + kk);
        }
#pragma unroll
        for (int g = 0; g < 5; ++g) {
            s16x8 bH = ld8(wh + (size_t)g * 512 * 1024 + k);
            s16x8 bL = ld8(wl + (size_t)g * 512 * 1024 + k);
#pragma unroll
            for (int t = 0; t < 4; ++t) {
                acc[t][g] = MFMA16(aH[t], bH, acc[t][g]);
                acc[t][g] = MFMA16(aH[t], bL, acc[t][g]);
                acc[t][g] = MFMA16(aL[t], bH, acc[t][g]);
            }
        }
    }
    int col = fg * 16 + l15;
    float bc[5];
#pragma unroll
    for (int g = 0; g < 5; ++g) bc[g] = b_comp[g * 512 + col];
    float qv = q[col];
#pragma unroll
    for (int t = 0; t < 4; ++t) {
#pragma unroll
        for (int rr = 0; rr < 4; ++rr) {
            int R = rg * 64 + t * 16 + quad * 4 + rr;
            int B_ = R / 63, J = R - B_ * 63;
            bool act = (J <= length[B_] - 2);
            float gi = acc[t][0][rr] + bc[0];
            float fl = acc[t][1][rr] + bc[1];
            float fr = acc[t][2][rr] + bc[2];
            float gu = acc[t][3][rr] + bc[3];
            float go = acc[t][4][rr] + bc[4];
            float cl = g_uc[((size_t)B_ * UROW + J) * 512 + col];
            float cr = g_uc[((size_t)B_ * UROW + J + 1) * 512 + col];
            float cn = cl * sigf(fl + 1.0f) + cr * sigf(fr + 1.0f) + tanhf(gu) * sigf(gi);
            float hn = sigf(go) * tanhf(cn);
            float sp = hn * qv;
#pragma unroll
            for (int off = 1; off < 16; off <<= 1) sp += __shfl_xor(sp, off, 16);
            if (act) {
                size_t o = ((size_t)B_ * UROW + 64 + J) * 512 + col;
                g_uhl[o] = packhl(hn);
                g_uc[o] = cn;
                g_candh[((size_t)B_ * NROW + J) * 512 + col] = hn;
                if (l15 == 0) g_spinit[(size_t)R * 32 + fg] = sp;
            }
        }
    }
}

// ---------------------------------------------------------------------------
// K_loop_p: ONE persistent kernel, 63 iterations. grid (32 fg, 8 rg) x 256.
// Round-7 idea (tagged score transport + deferred h/c flag poll) with two
// correctness fixes:
//  FIX1: g_spart2 is PARITY DOUBLE-BUFFERED. Producer at it writes parity
//        it&1 (tag it+1); consumer at it reads parity (it-1)&1 (tag it).
//        The slot a consumer reads at it is next overwritten only at it+1,
//        and any producer reaching it+1's epilogue has passed the flag[it]
//        poll, which requires every block's flag[it] store, which follows
//        that block's iteration-it read. (Single-buffered version could
//        overwrite before a stalled consumer's read -> tag skips -> spin
//        forever -> the round-7 hang.)
//  FIX2: the h/c flag poll runs for EVERY it>0 (not just it<62), so at
//        it=62 it orders flag[61] (all h/c stores) before the output phase.
// __launch_bounds__(256) — NOT (256,1), which broke cooperative launch.
// ---------------------------------------------------------------------------
__global__ __launch_bounds__(256) void k_loop_p(const int* __restrict__ length,
                                                const float* __restrict__ b_comp,
                                                const float* __restrict__ q,
                                                float* __restrict__ out) {
    int fg = blockIdx.x, rg = blockIdx.y;
    int tid = threadIdx.x;
    int wv = tid >> 6, lane = tid & 63;
    int l15 = lane & 15, quad = lane >> 4;
    const float sqrt_h = 22.627416997969522f;

    __shared__ int s_next[8][64], s_prev[8][64], s_aliv[8][64];
    __shared__ int s_enc[8][64];    // slot -> enc (<64 leaf, 64+candrow)
    __shared__ int s_prow[8][64];   // left-slot -> cand row of its current pair
    __shared__ float s_score[8][64];
    __shared__ int s_np[8][2];
    __shared__ int s_dl[16], s_dr[16], s_dd[16];
    __shared__ int s_len[8];
    __shared__ float s_red[4][64][21]; // all 4 waves' partials (stride 21)

    // ---- init: each wave builds its own 2 batches ----
    for (int bl = wv * 2; bl < wv * 2 + 2; ++bl) {
        int b = rg * 8 + bl;
        int len = length[b];
        if (lane == 0) { s_len[bl] = len; s_np[bl][0] = -1; s_np[bl][1] = -1; }
        s_next[bl][lane] = (lane < len - 1) ? lane + 1 : -1;
        s_prev[bl][lane] = (lane > 0 && lane < len) ? lane - 1 : -1;
        s_aliv[bl][lane] = (lane < len) ? 1 : 0;
        s_enc[bl][lane] = lane;
        s_prow[bl][lane] = lane;
        float sc = -3.0e38f;
        if (lane < 63 && lane <= len - 2) {
            float s = 0.0f;
            for (int f = 0; f < 32; ++f) s += g_spinit[(size_t)(b * 63 + lane) * 32 + f];
            sc = s / sqrt_h;
        }
        s_score[bl][lane] = sc;
    }
    __syncthreads();

    int col = fg * 16 + l15;
    float bc[5];
#pragma unroll
    for (int g = 0; g < 5; ++g) bc[g] = b_comp[g * 512 + col];
    float qv = q[col];
    const bf16* wh = g_wchi + (size_t)col * 1024;
    const bf16* wl = g_wclo + (size_t)col * 1024;

    for (int it = 0; it < 63; ++it) {
        // ------------- selection: wave w owns batches {2w, 2w+1} -----------
        for (int bl = wv * 2; bl < wv * 2 + 2; ++bl) {
            int len = s_len[bl];
            int r0 = bl * 2;
            bool active = (it <= len - 2);
            if (!active) {
                if (lane == 0) {
                    s_dl[r0] = 0; s_dr[r0] = 1; s_dd[r0] = -1;
                    s_dl[r0 + 1] = 0; s_dr[r0 + 1] = 1; s_dd[r0 + 1] = -1;
                }
                continue;
            }
            if (it > 0) {
                int s = lane >> 5, f = lane & 31;
                int p = s_np[bl][s];
                float v = 0.0f;
                if (p >= 0) {
                    // FIX1: parity (it-1)&1, tag it. Freshness + value in one
                    // atomic load; slot cannot be overwritten before this read.
                    const u64* sl = &g_spart2[((size_t)((it - 1) & 1) * 128
                                              + rg * 16 + r0 + s) * 32 + f];
                    u64 w = lda64u(sl);
                    while ((unsigned)(w >> 32) != (unsigned)it) {
                        __builtin_amdgcn_s_sleep(1);
                        w = lda64u(sl);
                    }
                    v = __builtin_bit_cast(float, (unsigned)(w & 0xffffffffu));
                }
#pragma unroll
                for (int off = 1; off < 32; off <<= 1) v += __shfl_xor(v, off, 32);
                if (f == 0 && p >= 0) s_score[bl][p] = v / sqrt_h;
            }
            float val = -3.0e38f;
            int idx = lane;
            if (lane < 63 && s_aliv[bl][lane] && s_next[bl][lane] >= 0)
                val = s_score[bl][lane];
#pragma unroll
            for (int off = 1; off < 64; off <<= 1) {
                float ov = __shfl_xor(val, off, 64);
                int oi = __shfl_xor(idx, off, 64);
                if (ov > val || (ov == val && oi < idx)) { val = ov; idx = oi; }
            }
            int a = idx;
            if (a < 0) a = 0;
            if (a > 62) a = 62;
            if (lane == 0) {
                int bn = s_next[bl][a];
                int nn = (bn >= 0) ? s_next[bl][bn] : -1;
                s_next[bl][a] = nn;
                if (nn >= 0) s_prev[bl][nn] = a;
                if (bn >= 0) s_aliv[bl][bn] = 0;
                s_enc[bl][a] = 64 + s_prow[bl][a];
                int pL = s_prev[bl][a];
                int pR = (nn >= 0) ? a : -1;
                s_np[bl][0] = pL;
                s_np[bl][1] = pR;
                if (pL >= 0) {
                    s_dl[r0] = s_enc[bl][pL]; s_dr[r0] = s_enc[bl][a];
                    s_dd[r0] = 63 + 2 * it;  s_prow[bl][pL] = 63 + 2 * it;
                } else { s_dl[r0] = 0; s_dr[r0] = 1; s_dd[r0] = -1; }
                if (pR >= 0) {
                    s_dl[r0 + 1] = s_enc[bl][a]; s_dr[r0 + 1] = s_enc[bl][nn];
                    s_dd[r0 + 1] = 63 + 2 * it + 1; s_prow[bl][a] = 63 + 2 * it + 1;
                } else { s_dl[r0 + 1] = 0; s_dr[r0 + 1] = 1; s_dd[r0 + 1] = -1; }
            }
        }
        __syncthreads();
        // FIX2: h/c readiness poll for every it>0 (also covers the output
        // phase after it=62). Propagation overlapped with selection above.
        if (it > 0) {
            const unsigned* fp = &g_flag[((size_t)(it - 1) * 8 + rg) * 32];
            for (;;) {
                unsigned fv = lda32(fp + (lane & 31));
                if (__all(fv != 0)) break;
                __builtin_amdgcn_s_sleep(1);
            }
            __atomic_signal_fence(__ATOMIC_SEQ_CST);
        }
        // ------------- GEMM: K split across 4 waves ------------------------
        if (it < 62) {
            int b_r = rg * 8 + (l15 >> 1);
            const unsigned* la = g_uhl + ((size_t)b_r * UROW + s_dl[l15]) * 512;
            const unsigned* ra = g_uhl + ((size_t)b_r * UROW + s_dr[l15]) * 512;
            const unsigned* base = (wv < 2) ? la : ra;   // kc<16 <=> k<512

            // (a) batch ALL A loads -> one L3 round trip instead of 8
            u64 ub[32];
#pragma unroll
            for (int i = 0; i < 8; ++i) {
                int kk = ((wv * 8 + i) * 32 + quad * 8) & 511;
                const unsigned* ap = base + kk;
                ub[4 * i + 0] = lda64(ap);
                ub[4 * i + 1] = lda64(ap + 2);
                ub[4 * i + 2] = lda64(ap + 4);
                ub[4 * i + 3] = lda64(ap + 6);
            }
            // (c) prefetch epilogue cl/cr for this wave's row (rowm = quad*4+wv)
            int rowm = quad * 4 + wv;
            int bb = rg * 8 + (rowm >> 1);
            float clv = ldaf(&g_uc[((size_t)bb * UROW + s_dl[rowm]) * 512 + col]);
            float crv = ldaf(&g_uc[((size_t)bb * UROW + s_dr[rowm]) * 512 + col]);

            f32x4 acc[5] = {};
#pragma unroll
            for (int i = 0; i < 8; ++i) {
                int k = (wv * 8 + i) * 32 + quad * 8;
                u64 u0 = ub[4 * i + 0], u1 = ub[4 * i + 1];
                u64 u2 = ub[4 * i + 2], u3 = ub[4 * i + 3];
                s16x8 aH, aL;
                aH[0] = (short)u0; aL[0] = (short)(u0 >> 16);
                aH[1] = (short)(u0 >> 32); aL[1] = (short)(u0 >> 48);
                aH[2] = (short)u1; aL[2] = (short)(u1 >> 16);
                aH[3] = (short)(u1 >> 32); aL[3] = (short)(u1 >> 48);
                aH[4] = (short)u2; aL[4] = (short)(u2 >> 16);
                aH[5] = (short)(u2 >> 32); aL[5] = (short)(u2 >> 48);
                aH[6] = (short)u3; aL[6] = (short)(u3 >> 16);
                aH[7] = (short)(u3 >> 32); aL[7] = (short)(u3 >> 48);
#pragma unroll
                for (int g = 0; g < 5; ++g) {
                    s16x8 bH = ld8(wh + (size_t)g * 512 * 1024 + k);
                    s16x8 bL = ld8(wl + (size_t)g * 512 * 1024 + k);
                    acc[g] = MFMA16(aH, bH, acc[g]);
                    acc[g] = MFMA16(aH, bL, acc[g]);
                    acc[g] = MFMA16(aL, bH, acc[g]);
                }
            }
            // (b) all waves publish partials; wave w reduces + finishes rr=w
#pragma unroll
            for (int g = 0; g < 5; ++g)
#pragma unroll
                for (int rr = 0; rr < 4; ++rr)
                    s_red[wv][lane][g * 4 + rr] = acc[g][rr];
            __syncthreads();
            {
                float accs[5];
#pragma unroll
                for (int g = 0; g < 5; ++g)
                    accs[g] = ((s_red[0][lane][g * 4 + wv] + s_red[1][lane][g * 4 + wv])
                               + s_red[2][lane][g * 4 + wv]) + s_red[3][lane][g * 4 + wv];
                int dest = s_dd[rowm];
                float gi = accs[0] + bc[0];
                float fl = accs[1] + bc[1];
                float fr = accs[2] + bc[2];
                float gu = accs[3] + bc[3];
                float go = accs[4] + bc[4];
                float cn = clv * sigf(fl + 1.0f) + crv * sigf(fr + 1.0f)
                           + tanhf(gu) * sigf(gi);
                float hn = sigf(go) * tanhf(cn);
                float sp = hn * qv;
#pragma unroll
                for (int off = 1; off < 16; off <<= 1) sp += __shfl_xor(sp, off, 16);
                if (dest >= 0) {
                    // tagged score FIRST: starts propagating while h/c store
                    if (l15 == 0) {
                        u64 w = ((u64)(unsigned)(it + 1) << 32)
                                | (u64)__builtin_bit_cast(unsigned, sp);
                        stau64(&g_spart2[((size_t)(it & 1) * 128
                                         + rg * 16 + rowm) * 32 + fg], w);
                    }
                    size_t o = ((size_t)bb * UROW + 64 + dest) * 512 + col;
                    stau(&g_uhl[o], packhl(hn));
                    staf(&g_uc[o], cn);
                    g_candh[((size_t)bb * NROW + dest) * 512 + col] = hn;
                }
            }
            // h/c readiness: drain own stores, rendezvous, one flag store
            __builtin_amdgcn_s_waitcnt(0);
            __syncthreads();
            if (tid == 0)
                stau(&g_flag[((size_t)it * 8 + rg) * 32 + fg], 1u);
        }
    }
    // ---------------- output: wave0, block-owned cols ----------------------
    if (wv == 0) {
        __builtin_amdgcn_s_waitcnt(0);
        for (int bl = 0; bl < 8; ++bl) {
            if ((lane >> 4) != (bl & 3)) continue;
            int b = rg * 8 + bl;
            int e0 = s_enc[bl][0];
            float hv, cv;
            if (e0 >= 64) {
                hv = g_candh[((size_t)b * NROW + e0 - 64) * 512 + col];
                cv = ldaf(&g_uc[((size_t)b * UROW + e0) * 512 + col]);
            } else {   // unreachable for len>=2, defensive
                unsigned u = g_uhl[((size_t)b * UROW + e0) * 512 + col];
                bf16 h0 = __builtin_bit_cast(bf16, (unsigned short)(u & 0xffff));
                bf16 l0 = __builtin_bit_cast(bf16, (unsigned short)(u >> 16));
                hv = (float)h0 + (float)l0;
                cv = ldaf(&g_uc[((size_t)b * UROW + e0) * 512 + col]);
            }
            out[(size_t)b * 512 + col] = hv;
            out[(size_t)(64 * 512) + b * 512 + col] = cv;
        }
    }
}

// ---------------------------------------------------------------------------
extern "C" void kernel_launch(void* const* d_in, const int* in_sizes, int n_in,
                              void* d_out, int out_size, void* d_ws, size_t ws_size,
                              hipStream_t stream) {
    const float* x = (const float*)d_in[0];
    const int* length = (const int*)d_in[1];
    const float* w_word = (const float*)d_in[2];
    const float* b_word = (const float*)d_in[3];
    const float* w_comp = (const float*)d_in[4];
    const float* b_comp = (const float*)d_in[5];
    const float* q = (const float*)d_in[6];
    float* out = (float*)d_out;

    unsigned* flagp;
    hipGetSymbolAddress((void**)&flagp, HIP_SYMBOL(g_flag));
    hipMemsetAsync(flagp, 0, 63 * 8 * 32 * sizeof(unsigned), stream);
    u64* sp2p;
    hipGetSymbolAddress((void**)&sp2p, HIP_SYMBOL(g_spart2));
    hipMemsetAsync(sp2p, 0, 2 * 128 * 32 * sizeof(u64), stream); // tags restart at 1

    hipLaunchKernelGGL(k_prep, dim3(2048), dim3(256), 0, stream, x, w_word, w_comp);
    hipLaunchKernelGGL(k_leaf, dim3(16, 256), dim3(64), 0, stream, b_word);
    hipLaunchKernelGGL(k_cells_init, dim3(32, 63), dim3(64), 0, stream,
                       length, b_comp, q);

    void* args[] = {(void*)&length, (void*)&b_comp, (void*)&q, (void*)&out};
    hipError_t ce = hipLaunchCooperativeKernel((void*)k_loop_p, dim3(32, 8),
                                               dim3(256), args, 0, stream);
    if (ce != hipSuccess) {
        // fallback: plain launch. 256 blocks on 256 CUs -> all co-resident;
        // the spin barriers do not require the cooperative API.
        hipLaunchKernelGGL(k_loop_p, dim3(32, 8), dim3(256), 0, stream,
                           length, b_comp, q, out);
    }
}

// Round 9
// 880.855 us; speedup vs baseline: 2.1023x; 1.6601x over previous
//
#include <hip/hip_runtime.h>

typedef __bf16 bf16;
typedef short s16x8 __attribute__((ext_vector_type(8)));
typedef float f32x4 __attribute__((ext_vector_type(4)));
typedef unsigned long long u64;

#define MFMA16(a, b, c) __builtin_amdgcn_mfma_f32_16x16x32_bf16((a), (b), (c), 0, 0, 0)
#define NROW 187   // cand rows per batch: 63 init + 2/iter
#define UROW 251   // unified rows: 64 leaf + 187 cand

__device__ __forceinline__ float sigf(float x) { return 1.0f / (1.0f + expf(-x)); }
__device__ __forceinline__ s16x8 ld8(const bf16* p) { return *(const s16x8*)p; }

__device__ __forceinline__ unsigned packhl(float v) {
    bf16 h = (bf16)v;
    bf16 l = (bf16)(v - (float)h);
    return (unsigned)__builtin_bit_cast(unsigned short, h) |
           ((unsigned)__builtin_bit_cast(unsigned short, l) << 16);
}
__device__ __forceinline__ u64 lda64(const unsigned* p) {
    return __hip_atomic_load((const u64*)p, __ATOMIC_RELAXED, __HIP_MEMORY_SCOPE_AGENT);
}
__device__ __forceinline__ u64 lda64u(const u64* p) {
    return __hip_atomic_load(p, __ATOMIC_RELAXED, __HIP_MEMORY_SCOPE_AGENT);
}
__device__ __forceinline__ void stau64(u64* p, u64 v) {
    __hip_atomic_store(p, v, __ATOMIC_RELAXED, __HIP_MEMORY_SCOPE_AGENT);
}
__device__ __forceinline__ unsigned lda32(const unsigned* p) {
    return __hip_atomic_load(p, __ATOMIC_RELAXED, __HIP_MEMORY_SCOPE_AGENT);
}
__device__ __forceinline__ float ldaf(const float* p) {
    return __hip_atomic_load(p, __ATOMIC_RELAXED, __HIP_MEMORY_SCOPE_AGENT);
}
__device__ __forceinline__ void staf(float* p, float v) {
    __hip_atomic_store(p, v, __ATOMIC_RELAXED, __HIP_MEMORY_SCOPE_AGENT);
}
__device__ __forceinline__ void stau(unsigned* p, unsigned v) {
    __hip_atomic_store(p, v, __ATOMIC_RELAXED, __HIP_MEMORY_SCOPE_AGENT);
}

// ---------------- device-global workspace (fp32 in / fp32 out) -------------
__device__ bf16  g_xhi[64 * 64 * 512], g_xlo[64 * 64 * 512];
__device__ bf16  g_wwhi[1024 * 512], g_wwlo[1024 * 512];
__device__ bf16  g_wchi[2560 * 1024], g_wclo[2560 * 1024];
__device__ bf16  g_hhi[64 * 64 * 512];              // leaf h hi (k_cells_init A)
__device__ bf16  g_hlo[64 * 64 * 512];              // leaf h lo
__device__ unsigned g_uhl[(size_t)64 * UROW * 512]; // unified h packed (hi|lo<<16)
__device__ float g_uc[(size_t)64 * UROW * 512];     // unified c fp32
__device__ float g_spinit[64 * 63 * 32];
__device__ u64   g_spart2[2 * 128 * 32];            // [parity][rg*16+row][fg]: tag<<32|sp
__device__ unsigned g_flag[63 * 8 * 32];            // [it][rg][fg] h/c ready flags

// ---------------- prep: all three fp32 -> bf16 hi/lo splits ----------------
__global__ __launch_bounds__(256) void k_prep(const float* __restrict__ x,
                                              const float* __restrict__ ww,
                                              const float* __restrict__ wc) {
    const int NX = 64 * 64 * 512, NW = 1024 * 512, NC = 2560 * 1024;
    int stride = gridDim.x * 256, i0 = blockIdx.x * 256 + threadIdx.x;
    for (int i = i0; i < NX; i += stride) {
        float v = x[i];
        bf16 h = (bf16)v;
        g_xhi[i] = h;
        g_xlo[i] = (bf16)(v - (float)h);
    }
    for (int i = i0; i < NW; i += stride) {
        float v = ww[i];
        bf16 h = (bf16)v;
        g_wwhi[i] = h;
        g_wwlo[i] = (bf16)(v - (float)h);
    }
    for (int i = i0; i < NC; i += stride) {
        float v = wc[i];
        bf16 h = (bf16)v;
        g_wchi[i] = h;
        g_wclo[i] = (bf16)(v - (float)h);
    }
}

// ---------------------------------------------------------------------------
// K0: leaf projection (M=4096, N=1024, K=512), 3-pass hi/lo MFMA.
// ---------------------------------------------------------------------------
__global__ __launch_bounds__(64) void k_leaf(const float* __restrict__ b_word) {
    int cg = blockIdx.x, rg = blockIdx.y;
    int lane = threadIdx.x, l15 = lane & 15, quad = lane >> 4;
    const bf16* axh = g_xhi + (size_t)(rg * 16 + l15) * 512;
    const bf16* axl = g_xlo + (size_t)(rg * 16 + l15) * 512;
    const bf16* bwh = g_wwhi + (size_t)(cg * 64 + l15) * 512;
    const bf16* bwl = g_wwlo + (size_t)(cg * 64 + l15) * 512;
    f32x4 acc[4] = {};
    for (int kc = 0; kc < 16; ++kc) {
        int k = kc * 32 + quad * 8;
        s16x8 aH = ld8(axh + k), aL = ld8(axl + k);
#pragma unroll
        for (int t = 0; t < 4; ++t) {
            s16x8 bH = ld8(bwh + (size_t)t * 16 * 512 + k);
            s16x8 bL = ld8(bwl + (size_t)t * 16 * 512 + k);
            acc[t] = MFMA16(aH, bH, acc[t]);
            acc[t] = MFMA16(aH, bL, acc[t]);
            acc[t] = MFMA16(aL, bH, acc[t]);
        }
    }
#pragma unroll
    for (int t = 0; t < 4; ++t) {
        int col = cg * 64 + t * 16 + l15;
        float bw = b_word[col];
#pragma unroll
        for (int r = 0; r < 4; ++r) {
            int m = rg * 16 + quad * 4 + r;
            int bb = m >> 6, sl = m & 63;
            float v = acc[t][r] + bw;
            if (col < 512) {
                bf16 hi = (bf16)v;
                g_hhi[(size_t)m * 512 + col] = hi;
                g_hlo[(size_t)m * 512 + col] = (bf16)(v - (float)hi);
                g_uhl[((size_t)bb * UROW + sl) * 512 + col] = packhl(v);
            } else {
                g_uc[((size_t)bb * UROW + sl) * 512 + (col - 512)] = v;
            }
        }
    }
}

// ---------------------------------------------------------------------------
// K1: initial candidates, all pairs (b,j) -> unified rows 64..126.
// ---------------------------------------------------------------------------
__global__ __launch_bounds__(64) void k_cells_init(const int* __restrict__ length,
                                                   const float* __restrict__ b_comp,
                                                   const float* __restrict__ q) {
    int fg = blockIdx.x;            // 0..31
    int rg = blockIdx.y;            // 0..62
    int lane = threadIdx.x, l15 = lane & 15, quad = lane >> 4;

    const bf16 *ahi[4], *alo[4];
#pragma unroll
    for (int t = 0; t < 4; ++t) {
        int r = rg * 64 + t * 16 + l15;      // pair row 0..4031
        int b = r / 63, j = r - b * 63;
        ahi[t] = g_hhi + (size_t)(b * 64 + j) * 512;
        alo[t] = g_hlo + (size_t)(b * 64 + j) * 512;
    }
    const bf16* wh = g_wchi + (size_t)(fg * 16 + l15) * 1024;
    const bf16* wl = g_wclo + (size_t)(fg * 16 + l15) * 1024;
    f32x4 acc[4][5] = {};
    for (int kc = 0; kc < 32; ++kc) {
        int k = kc * 32 + quad * 8;
        int kk = k & 511;
        size_t sh = (k < 512) ? 0 : 512;     // row j vs j+1 (contiguous rows)
        s16x8 aH[4], aL[4];
#pragma unroll
        for (int t = 0; t < 4; ++t) {
            aH[t] = ld8(ahi[t] + sh + kk);
            aL[t] = ld8(alo[t] + sh + kk);
        }
#pragma unroll
        for (int g = 0; g < 5; ++g) {
            s16x8 bH = ld8(wh + (size_t)g * 512 * 1024 + k);
            s16x8 bL = ld8(wl + (size_t)g * 512 * 1024 + k);
#pragma unroll
            for (int t = 0; t < 4; ++t) {
                acc[t][g] = MFMA16(aH[t], bH, acc[t][g]);
                acc[t][g] = MFMA16(aH[t], bL, acc[t][g]);
                acc[t][g] = MFMA16(aL[t], bH, acc[t][g]);
            }
        }
    }
    int col = fg * 16 + l15;
    float bc[5];
#pragma unroll
    for (int g = 0; g < 5; ++g) bc[g] = b_comp[g * 512 + col];
    float qv = q[col];
#pragma unroll
    for (int t = 0; t < 4; ++t) {
#pragma unroll
        for (int rr = 0; rr < 4; ++rr) {
            int R = rg * 64 + t * 16 + quad * 4 + rr;
            int B_ = R / 63, J = R - B_ * 63;
            bool act = (J <= length[B_] - 2);
            float gi = acc[t][0][rr] + bc[0];
            float fl = acc[t][1][rr] + bc[1];
            float fr = acc[t][2][rr] + bc[2];
            float gu = acc[t][3][rr] + bc[3];
            float go = acc[t][4][rr] + bc[4];
            float cl = g_uc[((size_t)B_ * UROW + J) * 512 + col];
            float cr = g_uc[((size_t)B_ * UROW + J + 1) * 512 + col];
            float cn = cl * sigf(fl + 1.0f) + cr * sigf(fr + 1.0f) + tanhf(gu) * sigf(gi);
            float hn = sigf(go) * tanhf(cn);
            float sp = hn * qv;
#pragma unroll
            for (int off = 1; off < 16; off <<= 1) sp += __shfl_xor(sp, off, 16);
            if (act) {
                size_t o = ((size_t)B_ * UROW + 64 + J) * 512 + col;
                g_uhl[o] = packhl(hn);
                g_uc[o] = cn;
                if (l15 == 0) g_spinit[(size_t)R * 32 + fg] = sp;
            }
        }
    }
}

// ---------------------------------------------------------------------------
// K_loop_p: ONE persistent kernel, 63 iterations. grid (32 fg, 8 rg) x 256.
// Round-8 structure + this round's changes:
//  * __launch_bounds__(256, 1): 1 wave/SIMD -> 512-VGPR budget. The kernel is
//    now PLAIN-launched unconditionally (spin barriers never needed the
//    cooperative API; 256 blocks = 256 CUs x 1 block/CU co-resident at any
//    VGPR count). Rounds 1-3 failed only because cooperative launch REJECTED
//    (256,1) and there was no fallback.
//  * B (w_comp slice) fully REGISTER-RESIDENT: rbH/rbL[8][5] (320 VGPRs)
//    loaded once; the per-iteration 320KB/block L2 B-stream (~2.4us) -> 0,
//    and the MFMA loop is pure-register.
//  * g_candh removed; output h decoded from packed g_uhl (err < 2^-16).
// ---------------------------------------------------------------------------
__global__ __launch_bounds__(256, 1) void k_loop_p(const int* __restrict__ length,
                                                   const float* __restrict__ b_comp,
                                                   const float* __restrict__ q,
                                                   float* __restrict__ out) {
    int fg = blockIdx.x, rg = blockIdx.y;
    int tid = threadIdx.x;
    int wv = tid >> 6, lane = tid & 63;
    int l15 = lane & 15, quad = lane >> 4;
    const float sqrt_h = 22.627416997969522f;

    __shared__ int s_next[8][64], s_prev[8][64], s_aliv[8][64];
    __shared__ int s_enc[8][64];    // slot -> enc (<64 leaf, 64+candrow)
    __shared__ int s_prow[8][64];   // left-slot -> cand row of its current pair
    __shared__ float s_score[8][64];
    __shared__ int s_np[8][2];
    __shared__ int s_dl[16], s_dr[16], s_dd[16];
    __shared__ int s_len[8];
    __shared__ float s_red[4][64][21]; // all 4 waves' partials (stride 21)

    // ---- init: each wave builds its own 2 batches ----
    for (int bl = wv * 2; bl < wv * 2 + 2; ++bl) {
        int b = rg * 8 + bl;
        int len = length[b];
        if (lane == 0) { s_len[bl] = len; s_np[bl][0] = -1; s_np[bl][1] = -1; }
        s_next[bl][lane] = (lane < len - 1) ? lane + 1 : -1;
        s_prev[bl][lane] = (lane > 0 && lane < len) ? lane - 1 : -1;
        s_aliv[bl][lane] = (lane < len) ? 1 : 0;
        s_enc[bl][lane] = lane;
        s_prow[bl][lane] = lane;
        float sc = -3.0e38f;
        if (lane < 63 && lane <= len - 2) {
            float s = 0.0f;
            for (int f = 0; f < 32; ++f) s += g_spinit[(size_t)(b * 63 + lane) * 32 + f];
            sc = s / sqrt_h;
        }
        s_score[bl][lane] = sc;
    }
    __syncthreads();

    int col = fg * 16 + l15;
    float bc[5];
#pragma unroll
    for (int g = 0; g < 5; ++g) bc[g] = b_comp[g * 512 + col];
    float qv = q[col];
    const bf16* wh = g_wchi + (size_t)col * 1024;
    const bf16* wl = g_wclo + (size_t)col * 1024;

    // ---- resident B: this wave's K-slice, held in VGPRs for all 62 iters --
    s16x8 rbH[8][5], rbL[8][5];
#pragma unroll
    for (int i = 0; i < 8; ++i) {
        int k = (wv * 8 + i) * 32 + quad * 8;
#pragma unroll
        for (int g = 0; g < 5; ++g) {
            rbH[i][g] = ld8(wh + (size_t)g * 512 * 1024 + k);
            rbL[i][g] = ld8(wl + (size_t)g * 512 * 1024 + k);
        }
    }

    for (int it = 0; it < 63; ++it) {
        // ------------- selection: wave w owns batches {2w, 2w+1} -----------
        for (int bl = wv * 2; bl < wv * 2 + 2; ++bl) {
            int len = s_len[bl];
            int r0 = bl * 2;
            bool active = (it <= len - 2);
            if (!active) {
                if (lane == 0) {
                    s_dl[r0] = 0; s_dr[r0] = 1; s_dd[r0] = -1;
                    s_dl[r0 + 1] = 0; s_dr[r0 + 1] = 1; s_dd[r0 + 1] = -1;
                }
                continue;
            }
            if (it > 0) {
                int s = lane >> 5, f = lane & 31;
                int p = s_np[bl][s];
                float v = 0.0f;
                if (p >= 0) {
                    // tagged poll: parity (it-1)&1, tag it; freshness + value
                    // in one atomic load (overwrite-before-read impossible:
                    // next overwrite requires all flag[it] stores, which
                    // follow every block's iteration-it read).
                    const u64* sl = &g_spart2[((size_t)((it - 1) & 1) * 128
                                              + rg * 16 + r0 + s) * 32 + f];
                    u64 w = lda64u(sl);
                    while ((unsigned)(w >> 32) != (unsigned)it) {
                        __builtin_amdgcn_s_sleep(1);
                        w = lda64u(sl);
                    }
                    v = __builtin_bit_cast(float, (unsigned)(w & 0xffffffffu));
                }
#pragma unroll
                for (int off = 1; off < 32; off <<= 1) v += __shfl_xor(v, off, 32);
                if (f == 0 && p >= 0) s_score[bl][p] = v / sqrt_h;
            }
            float val = -3.0e38f;
            int idx = lane;
            if (lane < 63 && s_aliv[bl][lane] && s_next[bl][lane] >= 0)
                val = s_score[bl][lane];
#pragma unroll
            for (int off = 1; off < 64; off <<= 1) {
                float ov = __shfl_xor(val, off, 64);
                int oi = __shfl_xor(idx, off, 64);
                if (ov > val || (ov == val && oi < idx)) { val = ov; idx = oi; }
            }
            int a = idx;
            if (a < 0) a = 0;
            if (a > 62) a = 62;
            if (lane == 0) {
                int bn = s_next[bl][a];
                int nn = (bn >= 0) ? s_next[bl][bn] : -1;
                s_next[bl][a] = nn;
                if (nn >= 0) s_prev[bl][nn] = a;
                if (bn >= 0) s_aliv[bl][bn] = 0;
                s_enc[bl][a] = 64 + s_prow[bl][a];
                int pL = s_prev[bl][a];
                int pR = (nn >= 0) ? a : -1;
                s_np[bl][0] = pL;
                s_np[bl][1] = pR;
                if (pL >= 0) {
                    s_dl[r0] = s_enc[bl][pL]; s_dr[r0] = s_enc[bl][a];
                    s_dd[r0] = 63 + 2 * it;  s_prow[bl][pL] = 63 + 2 * it;
                } else { s_dl[r0] = 0; s_dr[r0] = 1; s_dd[r0] = -1; }
                if (pR >= 0) {
                    s_dl[r0 + 1] = s_enc[bl][a]; s_dr[r0 + 1] = s_enc[bl][nn];
                    s_dd[r0 + 1] = 63 + 2 * it + 1; s_prow[bl][a] = 63 + 2 * it + 1;
                } else { s_dl[r0 + 1] = 0; s_dr[r0 + 1] = 1; s_dd[r0 + 1] = -1; }
            }
        }
        __syncthreads();
        // h/c readiness poll for every it>0 (also covers the output phase
        // after it=62). Propagation overlapped with the selection above.
        if (it > 0) {
            const unsigned* fp = &g_flag[((size_t)(it - 1) * 8 + rg) * 32];
            for (;;) {
                unsigned fv = lda32(fp + (lane & 31));
                if (__all(fv != 0)) break;
                __builtin_amdgcn_s_sleep(1);
            }
            __atomic_signal_fence(__ATOMIC_SEQ_CST);
        }
        // ------------- GEMM: K split across 4 waves ------------------------
        if (it < 62) {
            int b_r = rg * 8 + (l15 >> 1);
            const unsigned* la = g_uhl + ((size_t)b_r * UROW + s_dl[l15]) * 512;
            const unsigned* ra = g_uhl + ((size_t)b_r * UROW + s_dr[l15]) * 512;
            const unsigned* base = (wv < 2) ? la : ra;   // kc<16 <=> k<512

            // batch ALL A loads -> one L3 round trip instead of 8
            u64 ub[32];
#pragma unroll
            for (int i = 0; i < 8; ++i) {
                int kk = ((wv * 8 + i) * 32 + quad * 8) & 511;
                const unsigned* ap = base + kk;
                ub[4 * i + 0] = lda64(ap);
                ub[4 * i + 1] = lda64(ap + 2);
                ub[4 * i + 2] = lda64(ap + 4);
                ub[4 * i + 3] = lda64(ap + 6);
            }
            // prefetch epilogue cl/cr for this wave's row (rowm = quad*4+wv)
            int rowm = quad * 4 + wv;
            int bb = rg * 8 + (rowm >> 1);
            float clv = ldaf(&g_uc[((size_t)bb * UROW + s_dl[rowm]) * 512 + col]);
            float crv = ldaf(&g_uc[((size_t)bb * UROW + s_dr[rowm]) * 512 + col]);

            f32x4 acc[5] = {};
#pragma unroll
            for (int i = 0; i < 8; ++i) {
                u64 u0 = ub[4 * i + 0], u1 = ub[4 * i + 1];
                u64 u2 = ub[4 * i + 2], u3 = ub[4 * i + 3];
                s16x8 aH, aL;
                aH[0] = (short)u0; aL[0] = (short)(u0 >> 16);
                aH[1] = (short)(u0 >> 32); aL[1] = (short)(u0 >> 48);
                aH[2] = (short)u1; aL[2] = (short)(u1 >> 16);
                aH[3] = (short)(u1 >> 32); aL[3] = (short)(u1 >> 48);
                aH[4] = (short)u2; aL[4] = (short)(u2 >> 16);
                aH[5] = (short)(u2 >> 32); aL[5] = (short)(u2 >> 48);
                aH[6] = (short)u3; aL[6] = (short)(u3 >> 16);
                aH[7] = (short)(u3 >> 32); aL[7] = (short)(u3 >> 48);
#pragma unroll
                for (int g = 0; g < 5; ++g) {
                    acc[g] = MFMA16(aH, rbH[i][g], acc[g]);
                    acc[g] = MFMA16(aH, rbL[i][g], acc[g]);
                    acc[g] = MFMA16(aL, rbH[i][g], acc[g]);
                }
            }
            // all waves publish partials; wave w reduces + finishes rr=w
#pragma unroll
            for (int g = 0; g < 5; ++g)
#pragma unroll
                for (int rr = 0; rr < 4; ++rr)
                    s_red[wv][lane][g * 4 + rr] = acc[g][rr];
            __syncthreads();
            {
                float accs[5];
#pragma unroll
                for (int g = 0; g < 5; ++g)
                    accs[g] = ((s_red[0][lane][g * 4 + wv] + s_red[1][lane][g * 4 + wv])
                               + s_red[2][lane][g * 4 + wv]) + s_red[3][lane][g * 4 + wv];
                int dest = s_dd[rowm];
                float gi = accs[0] + bc[0];
                float fl = accs[1] + bc[1];
                float fr = accs[2] + bc[2];
                float gu = accs[3] + bc[3];
                float go = accs[4] + bc[4];
                float cn = clv * sigf(fl + 1.0f) + crv * sigf(fr + 1.0f)
                           + tanhf(gu) * sigf(gi);
                float hn = sigf(go) * tanhf(cn);
                float sp = hn * qv;
#pragma unroll
                for (int off = 1; off < 16; off <<= 1) sp += __shfl_xor(sp, off, 16);
                if (dest >= 0) {
                    // tagged score FIRST: starts propagating while h/c store
                    if (l15 == 0) {
                        u64 w = ((u64)(unsigned)(it + 1) << 32)
                                | (u64)__builtin_bit_cast(unsigned, sp);
                        stau64(&g_spart2[((size_t)(it & 1) * 128
                                         + rg * 16 + rowm) * 32 + fg], w);
                    }
                    size_t o = ((size_t)bb * UROW + 64 + dest) * 512 + col;
                    stau(&g_uhl[o], packhl(hn));
                    staf(&g_uc[o], cn);
                }
            }
            // h/c readiness: drain own stores, rendezvous, one flag store
            __builtin_amdgcn_s_waitcnt(0);
            __syncthreads();
            if (tid == 0)
                stau(&g_flag[((size_t)it * 8 + rg) * 32 + fg], 1u);
        }
    }
    // ---------------- output: wave0, block-owned cols ----------------------
    if (wv == 0) {
        __builtin_amdgcn_s_waitcnt(0);
        for (int bl = 0; bl < 8; ++bl) {
            if ((lane >> 4) != (bl & 3)) continue;
            int b = rg * 8 + bl;
            int e0 = s_enc[bl][0];
            unsigned u = lda32(&g_uhl[((size_t)b * UROW + e0) * 512 + col]);
            bf16 h0 = __builtin_bit_cast(bf16, (unsigned short)(u & 0xffffu));
            bf16 l0 = __builtin_bit_cast(bf16, (unsigned short)(u >> 16));
            float hv = (float)h0 + (float)l0;
            float cv = ldaf(&g_uc[((size_t)b * UROW + e0) * 512 + col]);
            out[(size_t)b * 512 + col] = hv;
            out[(size_t)(64 * 512) + b * 512 + col] = cv;
        }
    }
}

// ---------------------------------------------------------------------------
extern "C" void kernel_launch(void* const* d_in, const int* in_sizes, int n_in,
                              void* d_out, int out_size, void* d_ws, size_t ws_size,
                              hipStream_t stream) {
    const float* x = (const float*)d_in[0];
    const int* length = (const int*)d_in[1];
    const float* w_word = (const float*)d_in[2];
    const float* b_word = (const float*)d_in[3];
    const float* w_comp = (const float*)d_in[4];
    const float* b_comp = (const float*)d_in[5];
    const float* q = (const float*)d_in[6];
    float* out = (float*)d_out;

    unsigned* flagp;
    hipGetSymbolAddress((void**)&flagp, HIP_SYMBOL(g_flag));
    hipMemsetAsync(flagp, 0, 63 * 8 * 32 * sizeof(unsigned), stream);
    u64* sp2p;
    hipGetSymbolAddress((void**)&sp2p, HIP_SYMBOL(g_spart2));
    hipMemsetAsync(sp2p, 0, 2 * 128 * 32 * sizeof(u64), stream); // tags restart at 1

    hipLaunchKernelGGL(k_prep, dim3(2048), dim3(256), 0, stream, x, w_word, w_comp);
    hipLaunchKernelGGL(k_leaf, dim3(16, 256), dim3(64), 0, stream, b_word);
    hipLaunchKernelGGL(k_cells_init, dim3(32, 63), dim3(64), 0, stream,
                       length, b_comp, q);

    // Plain launch (no cooperative API): 256 blocks on 256 CUs, 1 block/CU
    // at any VGPR count -> all co-resident; spin barriers are self-contained.
    hipLaunchKernelGGL(k_loop_p, dim3(32, 8), dim3(256), 0, stream,
                       length, b_comp, q, out);
}